// Round 9
// baseline (5331.692 us; speedup 1.0000x reference)
//
#include <hip/hip_runtime.h>

// GRU scan, T=512 B=64 D=1024. Persistent cooperative kernel:
// 256 WGs = 4 independent mgrp groups x 64 col-WGs; 512 thr (8 waves, K 128/wave).
// Weights persistent in registers. NO barrier, NO flags: h exchanged as
// EPOCH-TAGGED words (payload16<<16 | epoch16, hi & lo planes); consumers poll
// their own coherent h loads until all tags == t. Poll waitcnt uses
// vm0() = s_waitcnt + sched_barrier(0)  (rule #18 -- the R7 NaN fix).
// x pre-split to bf16 hi/lo planes PER-MGRP inside d_out; out(t-1) deferred.

typedef __attribute__((ext_vector_type(8))) short short8;
typedef __attribute__((ext_vector_type(4))) float f32x4;
typedef __attribute__((ext_vector_type(4))) unsigned int u32x4;

#define DEV static __device__ __forceinline__

constexpr int TT = 512, BB = 64, DD = 1024, TD = 3072;

constexpr size_t WS_H = 8192;                    // tagged planes: hi0, lo0, hi1, lo1
constexpr size_t HP_BYTES = (size_t)BB * DD * 4; // u32 per element = 256 KB/plane
constexpr size_t WS_NEED = WS_H + 4 * HP_BYTES;  // ~1.03 MB

DEV unsigned short f2bf(float f) {   // RNE float->bf16
    unsigned u = __builtin_bit_cast(unsigned, f);
    u += 0x7FFFu + ((u >> 16) & 1u);
    return (unsigned short)(u >> 16);
}
DEV float bf2f(unsigned short s) { return __builtin_bit_cast(float, ((unsigned)s) << 16); }

DEV void ld16c(u32x4& r, const unsigned* p) {   // coherent 16B load (L1+L2 bypass)
    asm volatile("global_load_dwordx4 %0, %1, off sc0 sc1" : "=v"(r) : "v"(p));
}
DEV void ld16(u32x4& r, const unsigned* p) {    // plain cached 16B load
    asm volatile("global_load_dwordx4 %0, %1, off" : "=v"(r) : "v"(p));
}
DEV void ld8u(unsigned& r, const unsigned char* p) {
    asm volatile("global_load_ubyte %0, %1, off" : "=v"(r) : "v"(p));
}
DEV void vm0() {
    asm volatile("s_waitcnt vmcnt(0)" ::: "memory");
    __builtin_amdgcn_sched_barrier(0);   // rule #18: nothing crosses this point
}

// ---------------- prepass A: split x into bf16 hi/lo planes, MGRP-LOCAL layout ----------------
// plane t (65536 words): mgrp m: words [m*16384, +8192) = x_hi rows m*16..+16,
//                        words [m*16384+8192, +8192) = x_lo same rows.
__global__ void pack_x_kernel(const float* __restrict__ x, unsigned* __restrict__ outw) {
    const size_t gid = (size_t)blockIdx.x * 256 + threadIdx.x;
    const size_t e0 = gid * 8;
    const unsigned t = (unsigned)(e0 >> 16);
    const unsigned p = (unsigned)(e0 & 65535u);
    const unsigned r = p >> 10, d = p & 1023u;
    const unsigned m = r >> 4, lr = r & 15u;
    f32x4 a = *(const f32x4*)(x + e0);
    f32x4 b = *(const f32x4*)(x + e0 + 4);
    u32x4 wh, wl;
#pragma unroll
    for (int j = 0; j < 2; ++j) {
        unsigned short h0 = f2bf(a[2 * j]), h1 = f2bf(a[2 * j + 1]);
        wh[j] = (unsigned)h0 | ((unsigned)h1 << 16);
        wl[j] = (unsigned)f2bf(a[2 * j] - bf2f(h0)) | ((unsigned)f2bf(a[2 * j + 1] - bf2f(h1)) << 16);
        unsigned short g0 = f2bf(b[2 * j]), g1 = f2bf(b[2 * j + 1]);
        wh[2 + j] = (unsigned)g0 | ((unsigned)g1 << 16);
        wl[2 + j] = (unsigned)f2bf(b[2 * j] - bf2f(g0)) | ((unsigned)f2bf(b[2 * j + 1] - bf2f(g1)) << 16);
    }
    unsigned* base = outw + (size_t)t * 65536u + m * 16384u + ((lr * 1024u + d) >> 1);
    *(u32x4*)base = wh;
    *(u32x4*)(base + 8192u) = wl;
}

// ---------------- prepass B: zero buf0 planes (tag 0, h=0), detect resets stride ----------------
__global__ void prep_kernel(const unsigned char* __restrict__ resets, unsigned char* __restrict__ ws) {
    const int bid = blockIdx.x, tid = threadIdx.x;
    if (bid < 512) {
        // zero hi0+lo0: 512 KB = 512 x 256 x 4B
        ((unsigned*)(ws + WS_H))[bid * 256 + tid] = 0u;
    } else {
        unsigned* w32 = (unsigned*)ws;
        for (int i = tid; i < 2048; i += 256) w32[i] = 0u;
        __shared__ int ca, cb, cc;
        if (tid == 0) { ca = 0; cb = 0; cc = 0; }
        __syncthreads();
        int la = 0, lb = 0, lc = 0;
        for (int o = tid * 16; o < tid * 16 + 16; ++o) {
            unsigned char v = resets[o];
            if (v) {
                if ((o & 3) == 0) la = 1; else lb = 1;
                if ((o & 7) == 4) lc = 1;
            }
        }
        if (la) atomicOr(&ca, 1);
        if (lb) atomicOr(&cb, 1);
        if (lc) atomicOr(&cc, 1);
        __syncthreads();
        if (tid == 0) {
            unsigned stride, boff = 0;
            if (ca && cb)       { stride = 1; }
            else if (!ca && cb) { stride = 4; boff = 3; }
            else if (ca && cc)  { stride = 4; }
            else if (ca)        { stride = 8; }
            else                { stride = 4; }
            w32[0] = stride; w32[1] = boff;
        }
    }
}

// ---------------- main persistent kernel ----------------
__launch_bounds__(512, 1)
__global__ void gru_kernel(const float* __restrict__ Wi, const float* __restrict__ bi,
                           const float* __restrict__ Wh, const float* __restrict__ bhn,
                           const unsigned char* __restrict__ resets,
                           float* __restrict__ out, unsigned char* __restrict__ ws) {
    const int tid = threadIdx.x;
    const int wg = blockIdx.x;
    const int lane = tid & 63;
    const int kw = tid >> 6;
    const int mgrp = wg >> 6;
    const int cg = wg & 63;
    const int c0 = cg * 16;

    const unsigned rstride = ((const unsigned*)ws)[0];
    const unsigned rboff   = ((const unsigned*)ws)[1];

    unsigned* h_hi[2] = {(unsigned*)(ws + WS_H),
                         (unsigned*)(ws + WS_H + 2 * HP_BYTES)};
    unsigned* h_lo[2] = {(unsigned*)(ws + WS_H + HP_BYTES),
                         (unsigned*)(ws + WS_H + 3 * HP_BYTES)};
    unsigned* outw = (unsigned*)out;

    const int lrow = lane & 15;
    const int lk = (lane >> 4) * 8;

    // ---- persistent B fragments (Wi_hi, Wh_hi, Wh_lo) ----
    short8 bih[3][4], bhh[3][4], bhl[3][4];
#pragma unroll
    for (int nt = 0; nt < 3; ++nt) {
        const int col = nt * DD + c0 + lrow;
#pragma unroll
        for (int kt = 0; kt < 4; ++kt) {
            const int kb = kw * 128 + kt * 32 + lk;
            short8 a, c, d;
#pragma unroll
            for (int j = 0; j < 8; ++j) {
                float wi = Wi[(size_t)(kb + j) * TD + col];
                a[j] = (short)f2bf(wi);
                float wh = Wh[(size_t)(kb + j) * TD + col];
                unsigned short h2 = f2bf(wh);
                c[j] = (short)h2;
                d[j] = (short)f2bf(wh - bf2f(h2));
            }
            bih[nt][kt] = a; bhh[nt][kt] = c; bhl[nt][kt] = d;
        }
    }

    // ---- epilogue constants ----
    const int eb = (tid & 255) >> 4, ej = tid & 15;
    const int brow = mgrp * 16 + eb;
    const int ce = c0 + ej;
    const float bi_r = bi[ce], bi_z = bi[DD + ce], bi_n = bi[2 * DD + ce];
    const float bh_n = bhn[ce];
    float h_local = 0.f;
    float ys_prev = 0.f;

    const unsigned xlidx = (unsigned)(lrow * 1024 + kw * 128 + lk);
    const unsigned xwbase = (unsigned)mgrp * 16384u + (xlidx >> 1);
    const unsigned hidx = (unsigned)((mgrp * 16 + lrow) * 1024 + kw * 128 + lk); // u32 idx
    const size_t r64 = (size_t)64 * rstride;
    const size_t roffb = (size_t)brow * rstride + rboff;

    __shared__ float pgi[8][3][16][17];
    __shared__ float pgh[8][3][16][17];
    const int prow = (lane >> 4) * 4;

    // ================= prologue: gi(0) =================
    {
        const unsigned* xpl = outw;   // plane 0
        u32x4 xf[8];
#pragma unroll
        for (int kt = 0; kt < 4; ++kt) {
            ld16(xf[2 * kt],     xpl + xwbase + kt * 16);
            ld16(xf[2 * kt + 1], xpl + xwbase + 8192u + kt * 16);
        }
        vm0();
        f32x4 ai[3] = {f32x4{0}, f32x4{0}, f32x4{0}};
#pragma unroll
        for (int kt = 0; kt < 4; ++kt) {
            short8 xh = __builtin_bit_cast(short8, xf[2 * kt]);
            short8 xl = __builtin_bit_cast(short8, xf[2 * kt + 1]);
#pragma unroll
            for (int nt = 0; nt < 3; ++nt)
                ai[nt] = __builtin_amdgcn_mfma_f32_16x16x32_bf16(xh, bih[nt][kt], ai[nt], 0, 0, 0);
#pragma unroll
            for (int nt = 0; nt < 3; ++nt)
                ai[nt] = __builtin_amdgcn_mfma_f32_16x16x32_bf16(xl, bih[nt][kt], ai[nt], 0, 0, 0);
        }
#pragma unroll
        for (int s = 0; s < 3; ++s)
#pragma unroll
            for (int i = 0; i < 4; ++i)
                pgi[kw][s][lrow][prow + i] = ai[s][i];
        __syncthreads();
    }

    // ================= main loop =================
    for (int t = 0; t < TT; ++t) {
        const int tn = (t + 1 < TT) ? (t + 1) : (TT - 1);

        // (1) issue rsv + x(t+1) loads (latency hidden under the h poll)
        unsigned rsv;
        ld8u(rsv, resets + roffb + (size_t)tn * r64);
        const unsigned* xpl = outw + (size_t)tn * 65536u;
        u32x4 xf[8];
#pragma unroll
        for (int kt = 0; kt < 4; ++kt) {
            ld16(xf[2 * kt],     xpl + xwbase + kt * 16);
            ld16(xf[2 * kt + 1], xpl + xwbase + 8192u + kt * 16);
        }

        // (2) POLL: tagged h loads; the data load IS the synchronization
        const int cur = t & 1;
        const unsigned* hip_ = h_hi[cur] + hidx;
        const unsigned* hlp_ = h_lo[cur] + hidx;
        const unsigned tag = (unsigned)t & 0xFFFFu;
        u32x4 ph[8], pl[8];
        {
            int guard = 1 << 20;   // bounded spin: fail loud, never hang
            while (true) {
#pragma unroll
                for (int kt = 0; kt < 4; ++kt) {
                    ld16c(ph[2 * kt],     hip_ + kt * 32);
                    ld16c(ph[2 * kt + 1], hip_ + kt * 32 + 4);
                    ld16c(pl[2 * kt],     hlp_ + kt * 32);
                    ld16c(pl[2 * kt + 1], hlp_ + kt * 32 + 4);
                }
                vm0();   // drains h loads (and, first pass, rsv+x)
                unsigned bad = 0;
#pragma unroll
                for (int i = 0; i < 8; ++i)
#pragma unroll
                    for (int j = 0; j < 4; ++j)
                        bad |= ((ph[i][j] ^ tag) | (pl[i][j] ^ tag)) & 0xFFFFu;
                if (__all(bad == 0) || --guard == 0) break;
            }
        }

        // (3) gi reduce (LDS only)
        float g0 = 0.f, g1 = 0.f, g2 = 0.f;
        if (tid < 256) {
#pragma unroll
            for (int k = 0; k < 8; ++k) {
                g0 += pgi[k][0][ej][eb];
                g1 += pgi[k][1][ej][eb];
                g2 += pgi[k][2][ej][eb];
            }
        }

        // (4) gh MFMAs (h already in registers)
        f32x4 ag[3] = {f32x4{0}, f32x4{0}, f32x4{0}};
        __builtin_amdgcn_s_setprio(1);
#pragma unroll
        for (int kt = 0; kt < 4; ++kt) {
            u32x4 wh, wl;
            wh[0] = (ph[2 * kt][0] >> 16)     | (ph[2 * kt][1] & 0xFFFF0000u);
            wh[1] = (ph[2 * kt][2] >> 16)     | (ph[2 * kt][3] & 0xFFFF0000u);
            wh[2] = (ph[2 * kt + 1][0] >> 16) | (ph[2 * kt + 1][1] & 0xFFFF0000u);
            wh[3] = (ph[2 * kt + 1][2] >> 16) | (ph[2 * kt + 1][3] & 0xFFFF0000u);
            wl[0] = (pl[2 * kt][0] >> 16)     | (pl[2 * kt][1] & 0xFFFF0000u);
            wl[1] = (pl[2 * kt][2] >> 16)     | (pl[2 * kt][3] & 0xFFFF0000u);
            wl[2] = (pl[2 * kt + 1][0] >> 16) | (pl[2 * kt + 1][1] & 0xFFFF0000u);
            wl[3] = (pl[2 * kt + 1][2] >> 16) | (pl[2 * kt + 1][3] & 0xFFFF0000u);
            short8 hh = __builtin_bit_cast(short8, wh);
            short8 hl = __builtin_bit_cast(short8, wl);
#pragma unroll
            for (int nt = 0; nt < 3; ++nt) {
                ag[nt] = __builtin_amdgcn_mfma_f32_16x16x32_bf16(hh, bhh[nt][kt], ag[nt], 0, 0, 0);
                ag[nt] = __builtin_amdgcn_mfma_f32_16x16x32_bf16(hl, bhh[nt][kt], ag[nt], 0, 0, 0);
                ag[nt] = __builtin_amdgcn_mfma_f32_16x16x32_bf16(hh, bhl[nt][kt], ag[nt], 0, 0, 0);
            }
        }
        __builtin_amdgcn_s_setprio(0);

        // (5) publish gh partials
#pragma unroll
        for (int s = 0; s < 3; ++s)
#pragma unroll
            for (int i = 0; i < 4; ++i)
                pgh[kw][s][lrow][prow + i] = ag[s][i];
        __syncthreads();

        // (6) epilogue (waves 0-3): gates, deferred out(t-1), tagged h(t+1) stores
        if (tid < 256) {
            float h0 = 0.f, h1 = 0.f, h2 = 0.f;
#pragma unroll
            for (int k = 0; k < 8; ++k) {
                h0 += pgh[k][0][ej][eb];
                h1 += pgh[k][1][ej][eb];
                h2 += pgh[k][2][ej][eb];
            }
            float r = 1.f / (1.f + __expf(-(g0 + bi_r + h0)));
            float z = 1.f / (1.f + __expf(-(g1 + bi_z + h1)));
            float pre = g2 + bi_n + r * (h2 + bh_n);
            float e2 = __expf(2.f * pre);
            float n = 1.f - 2.f / (e2 + 1.f);
            float hnew = (1.f - z) * n + z * h_local;

            if (t) out[(size_t)(t - 1) * 65536u + brow * DD + ce] = ys_prev;
            ys_prev = hnew;

            if (t < TT - 1) {
                float heff = (rsv != 0u) ? 0.f : hnew;   // rsv drained by poll's vm0
                h_local = heff;
                const unsigned ntag = (unsigned)(t + 1) & 0xFFFFu;
                unsigned short ph16 = f2bf(heff);
                unsigned short pl16 = f2bf(heff - bf2f(ph16));
                __hip_atomic_store(h_hi[cur ^ 1] + brow * 1024 + ce,
                                   ((unsigned)ph16 << 16) | ntag,
                                   __ATOMIC_RELAXED, __HIP_MEMORY_SCOPE_AGENT);
                __hip_atomic_store(h_lo[cur ^ 1] + brow * 1024 + ce,
                                   ((unsigned)pl16 << 16) | ntag,
                                   __ATOMIC_RELAXED, __HIP_MEMORY_SCOPE_AGENT);
            }
        }

        // (7) tail: gi(t+1) from prefetched x (already in registers)
        if (t < TT - 1) {
            f32x4 ai[3] = {f32x4{0}, f32x4{0}, f32x4{0}};
#pragma unroll
            for (int kt = 0; kt < 4; ++kt) {
                short8 xh = __builtin_bit_cast(short8, xf[2 * kt]);
                short8 xl = __builtin_bit_cast(short8, xf[2 * kt + 1]);
#pragma unroll
                for (int nt = 0; nt < 3; ++nt)
                    ai[nt] = __builtin_amdgcn_mfma_f32_16x16x32_bf16(xh, bih[nt][kt], ai[nt], 0, 0, 0);
#pragma unroll
                for (int nt = 0; nt < 3; ++nt)
                    ai[nt] = __builtin_amdgcn_mfma_f32_16x16x32_bf16(xl, bih[nt][kt], ai[nt], 0, 0, 0);
            }
#pragma unroll
            for (int s = 0; s < 3; ++s)
#pragma unroll
                for (int i = 0; i < 4; ++i)
                    pgi[kw][s][lrow][prow + i] = ai[s][i];
            __syncthreads();
        }
    }

    if (tid < 256)
        out[(size_t)(TT - 1) * 65536u + brow * DD + ce] = ys_prev;
}

extern "C" void kernel_launch(void* const* d_in, const int* in_sizes, int n_in,
                              void* d_out, int out_size, void* d_ws, size_t ws_size,
                              hipStream_t stream) {
    const float* x = (const float*)d_in[0];
    const float* Wi = (const float*)d_in[1];
    const float* bi = (const float*)d_in[2];
    const float* Wh = (const float*)d_in[3];
    const float* bhn = (const float*)d_in[4];
    const unsigned char* resets = (const unsigned char*)d_in[5];
    float* out = (float*)d_out;
    unsigned char* ws = (unsigned char*)d_ws;

    if (ws_size < WS_NEED) return;

    hipLaunchKernelGGL(pack_x_kernel, dim3(16384), dim3(256), 0, stream, x, (unsigned*)out);
    hipLaunchKernelGGL(prep_kernel, dim3(513), dim3(256), 0, stream, resets, ws);

    void* args[] = {(void*)&Wi, (void*)&bi, (void*)&Wh, (void*)&bhn,
                    (void*)&resets, (void*)&out, (void*)&ws};
    hipError_t err = hipLaunchCooperativeKernel((const void*)gru_kernel, dim3(256), dim3(512),
                                                args, 0, stream);
    if (err != hipSuccess) {
        hipLaunchKernelGGL(gru_kernel, dim3(256), dim3(512), 0, stream,
                           Wi, bi, Wh, bhn, resets, out, ws);
    }
}

// Round 10
// 3283.747 us; speedup vs baseline: 1.6237x; 1.6237x over previous
//
#include <hip/hip_runtime.h>

// GRU scan, T=512 B=64 D=1024. Persistent cooperative kernel:
// 256 WGs = 4 independent mgrp groups x 64 col-WGs; 512 thr (8 waves, K 128/wave).
// Weights persistent in registers/AGPRs. R6-proven sync fabric:
//   - arrivals: ONE fetch_add per WG per step (8 replica lines per mgrp)
//   - poll: all waves, 8 wave-uniform __hip_atomic_loads (broadcast-coalesced)
// Critical-path order per step:
//   poll -> issue rsv+h(sc0sc1) -> WAITN(9) (drain x) -> gi MFMAs (h in flight)
//   -> counted WAITN gh MFMAs -> publish both -> sync -> reduce -> gates
//   -> out(t-1)+h(t+1) stores -> per-wave vm0 -> sync -> tid0 arrive
//   -> issue x(t+1) (drains during next poll)
// x pre-split to bf16 hi/lo planes PER-MGRP inside d_out (race-free by epochs).

typedef __attribute__((ext_vector_type(8))) short short8;
typedef __attribute__((ext_vector_type(4))) float f32x4;
typedef __attribute__((ext_vector_type(4))) unsigned int u32x4;

#define DEV static __device__ __forceinline__

constexpr int TT = 512, BB = 64, DD = 1024, TD = 3072;

constexpr size_t WS_BAR = 256;                 // words 64..: 4 mgrps x 8 replicas x 32 words
constexpr size_t WS_H = 8192;                  // h planes: hb0_hi, hb0_lo, hb1_hi, hb1_lo
constexpr size_t HPLANE = (size_t)BB * DD * 2; // 128 KB per plane
constexpr size_t WS_NEED = WS_H + 4 * HPLANE;

DEV unsigned short f2bf(float f) {   // RNE float->bf16
    unsigned u = __builtin_bit_cast(unsigned, f);
    u += 0x7FFFu + ((u >> 16) & 1u);
    return (unsigned short)(u >> 16);
}
DEV float bf2f(unsigned short s) { return __builtin_bit_cast(float, ((unsigned)s) << 16); }

DEV void ld16c(u32x4& r, const unsigned* p) {   // coherent 16B load (L1+L2 bypass)
    asm volatile("global_load_dwordx4 %0, %1, off sc0 sc1" : "=v"(r) : "v"(p));
}
DEV void ld16(u32x4& r, const unsigned* p) {    // plain cached 16B load
    asm volatile("global_load_dwordx4 %0, %1, off" : "=v"(r) : "v"(p));
}
DEV void ld8u(unsigned& r, const unsigned char* p) {
    asm volatile("global_load_ubyte %0, %1, off" : "=v"(r) : "v"(p));
}
DEV void vm0() {
    asm volatile("s_waitcnt vmcnt(0)" ::: "memory");
    __builtin_amdgcn_sched_barrier(0);   // rule #18
}
#define WAITN(n) do { asm volatile("s_waitcnt vmcnt(" #n ")" ::: "memory"); \
                      __builtin_amdgcn_sched_barrier(0); } while (0)

// ---------------- prepass A: split x into bf16 hi/lo planes, MGRP-LOCAL layout ----------------
// plane t (65536 words): mgrp m: words [m*16384, +8192) = x_hi rows m*16..+16,
//                        words [m*16384+8192, +8192) = x_lo same rows.
__global__ void pack_x_kernel(const float* __restrict__ x, unsigned* __restrict__ outw) {
    const size_t gid = (size_t)blockIdx.x * 256 + threadIdx.x;
    const size_t e0 = gid * 8;
    const unsigned t = (unsigned)(e0 >> 16);
    const unsigned p = (unsigned)(e0 & 65535u);
    const unsigned r = p >> 10, d = p & 1023u;
    const unsigned m = r >> 4, lr = r & 15u;
    f32x4 a = *(const f32x4*)(x + e0);
    f32x4 b = *(const f32x4*)(x + e0 + 4);
    u32x4 wh, wl;
#pragma unroll
    for (int j = 0; j < 2; ++j) {
        unsigned short h0 = f2bf(a[2 * j]), h1 = f2bf(a[2 * j + 1]);
        wh[j] = (unsigned)h0 | ((unsigned)h1 << 16);
        wl[j] = (unsigned)f2bf(a[2 * j] - bf2f(h0)) | ((unsigned)f2bf(a[2 * j + 1] - bf2f(h1)) << 16);
        unsigned short g0 = f2bf(b[2 * j]), g1 = f2bf(b[2 * j + 1]);
        wh[2 + j] = (unsigned)g0 | ((unsigned)g1 << 16);
        wl[2 + j] = (unsigned)f2bf(b[2 * j] - bf2f(g0)) | ((unsigned)f2bf(b[2 * j + 1] - bf2f(g1)) << 16);
    }
    unsigned* base = outw + (size_t)t * 65536u + m * 16384u + ((lr * 1024u + d) >> 1);
    *(u32x4*)base = wh;
    *(u32x4*)(base + 8192u) = wl;
}

// ---------------- prepass B: zero h-buf0 + barrier area, detect resets stride ----------------
__global__ void prep_kernel(const unsigned char* __restrict__ resets, unsigned char* __restrict__ ws) {
    const int bid = blockIdx.x, tid = threadIdx.x;
    if (bid < 256) {
        ((unsigned*)(ws + WS_H))[bid * 256 + tid] = 0u;   // zero hb0 hi+lo (256 KB)
    } else {
        unsigned* w32 = (unsigned*)ws;
        for (int i = tid; i < 2048; i += 256) w32[i] = 0u;
        __shared__ int ca, cb, cc;
        if (tid == 0) { ca = 0; cb = 0; cc = 0; }
        __syncthreads();
        int la = 0, lb = 0, lc = 0;
        for (int o = tid * 16; o < tid * 16 + 16; ++o) {
            unsigned char v = resets[o];
            if (v) {
                if ((o & 3) == 0) la = 1; else lb = 1;
                if ((o & 7) == 4) lc = 1;
            }
        }
        if (la) atomicOr(&ca, 1);
        if (lb) atomicOr(&cb, 1);
        if (lc) atomicOr(&cc, 1);
        __syncthreads();
        if (tid == 0) {
            unsigned stride, boff = 0;
            if (ca && cb)       { stride = 1; }
            else if (!ca && cb) { stride = 4; boff = 3; }
            else if (ca && cc)  { stride = 4; }
            else if (ca)        { stride = 8; }
            else                { stride = 4; }
            w32[0] = stride; w32[1] = boff;
        }
    }
}

// ---------------- main persistent kernel ----------------
__launch_bounds__(512, 1)
__global__ void gru_kernel(const float* __restrict__ Wi, const float* __restrict__ bi,
                           const float* __restrict__ Wh, const float* __restrict__ bhn,
                           const unsigned char* __restrict__ resets,
                           float* __restrict__ out, unsigned char* __restrict__ ws) {
    const int tid = threadIdx.x;
    const int wg = blockIdx.x;
    const int lane = tid & 63;
    const int kw = tid >> 6;
    const int mgrp = wg >> 6;
    const int cg = wg & 63;
    const int c0 = cg * 16;

    unsigned* bar = (unsigned*)(ws + WS_BAR) + mgrp * 256;   // 8 replicas at r*32 words
    unsigned* rep = &bar[(cg & 7) * 32];
    const unsigned rstride = ((const unsigned*)ws)[0];
    const unsigned rboff   = ((const unsigned*)ws)[1];

    unsigned short* h_hi[2] = {(unsigned short*)(ws + WS_H),
                               (unsigned short*)(ws + WS_H + 2 * HPLANE)};
    unsigned short* h_lo[2] = {(unsigned short*)(ws + WS_H + HPLANE),
                               (unsigned short*)(ws + WS_H + 3 * HPLANE)};
    unsigned* outw = (unsigned*)out;

    const int lrow = lane & 15;
    const int lk = (lane >> 4) * 8;

    // ---- persistent B fragments (Wi_hi, Wh_hi, Wh_lo) ----
    short8 bih[3][4], bhh[3][4], bhl[3][4];
#pragma unroll
    for (int nt = 0; nt < 3; ++nt) {
        const int col = nt * DD + c0 + lrow;
#pragma unroll
        for (int kt = 0; kt < 4; ++kt) {
            const int kb = kw * 128 + kt * 32 + lk;
            short8 a, c, d;
#pragma unroll
            for (int j = 0; j < 8; ++j) {
                float wi = Wi[(size_t)(kb + j) * TD + col];
                a[j] = (short)f2bf(wi);
                float wh = Wh[(size_t)(kb + j) * TD + col];
                unsigned short h2 = f2bf(wh);
                c[j] = (short)h2;
                d[j] = (short)f2bf(wh - bf2f(h2));
            }
            bih[nt][kt] = a; bhh[nt][kt] = c; bhl[nt][kt] = d;
        }
    }

    // ---- epilogue constants ----
    const int eb = (tid & 255) >> 4, ej = tid & 15;
    const int brow = mgrp * 16 + eb;
    const int ce = c0 + ej;
    const float bi_r = bi[ce], bi_z = bi[DD + ce], bi_n = bi[2 * DD + ce];
    const float bh_n = bhn[ce];
    float h_local = 0.f;
    float ys_prev = 0.f;

    const unsigned xlidx = (unsigned)(lrow * 1024 + kw * 128 + lk);
    const unsigned xwbase = (unsigned)mgrp * 16384u + (xlidx >> 1);
    const unsigned hidx = (unsigned)((mgrp * 16 + lrow) * 1024 + kw * 128 + lk);
    const size_t r64 = (size_t)64 * rstride;
    const size_t roffb = (size_t)brow * rstride + rboff;

    __shared__ float pgi[8][3][16][17];
    __shared__ float pgh[8][3][16][17];
    const int prow = (lane >> 4) * 4;

    // ================= prologue: issue x(0) loads, arrive epoch 1 =================
    u32x4 xf[8];
    {
        const unsigned* xpl = outw;   // plane 0
#pragma unroll
        for (int kt = 0; kt < 4; ++kt) {
            ld16(xf[2 * kt],     xpl + xwbase + kt * 16);
            ld16(xf[2 * kt + 1], xpl + xwbase + 8192u + kt * 16);
        }
        if (tid == 0)
            __hip_atomic_fetch_add(rep, 1u, __ATOMIC_RELAXED, __HIP_MEMORY_SCOPE_AGENT);
    }

    // ================= main loop =================
    for (int t = 0; t < TT; ++t) {
        // (a) poll: sum of 8 replicas >= 64*(t+1); wave-uniform atomic loads.
        //     (x loads drain under this wait -- their latency is off-path.)
        {
            const unsigned target = 64u * (unsigned)(t + 1);
            int guard = 1 << 20;   // bounded spin: fail loud, never hang
            unsigned s;
            do {
                s = 0;
#pragma unroll
                for (int r2 = 0; r2 < 8; ++r2)
                    s += __hip_atomic_load(&bar[r2 * 32], __ATOMIC_RELAXED, __HIP_MEMORY_SCOPE_AGENT);
            } while (s < target && --guard);
        }
        __builtin_amdgcn_sched_barrier(0);

        const int tn = (t + 1 < TT) ? (t + 1) : (TT - 1);

        // (b) issue: rsv byte + coherent h(t) loads  (queue: [x8][rsv][h8] = 17)
        unsigned rsv;
        ld8u(rsv, resets + roffb + (size_t)tn * r64);
        const int cur = t & 1;
        const unsigned* hhp = (const unsigned*)h_hi[cur];
        const unsigned* hlp = (const unsigned*)h_lo[cur];
        u32x4 hf[8];
#pragma unroll
        for (int kt = 0; kt < 4; ++kt) {
            ld16c(hf[2 * kt],     hhp + ((hidx + kt * 32) >> 1));
            ld16c(hf[2 * kt + 1], hlp + ((hidx + kt * 32) >> 1));
        }

        // (c) drain x, run gi MFMAs while h is in flight
        WAITN(9);
        f32x4 ai[3] = {f32x4{0}, f32x4{0}, f32x4{0}};
#pragma unroll
        for (int kt = 0; kt < 4; ++kt) {
            short8 xh = __builtin_bit_cast(short8, xf[2 * kt]);
            short8 xl = __builtin_bit_cast(short8, xf[2 * kt + 1]);
#pragma unroll
            for (int nt = 0; nt < 3; ++nt)
                ai[nt] = __builtin_amdgcn_mfma_f32_16x16x32_bf16(xh, bih[nt][kt], ai[nt], 0, 0, 0);
#pragma unroll
            for (int nt = 0; nt < 3; ++nt)
                ai[nt] = __builtin_amdgcn_mfma_f32_16x16x32_bf16(xl, bih[nt][kt], ai[nt], 0, 0, 0);
        }

        // (e) gh MFMAs with counted waits (queue after (c): [rsv][h0..h7])
        f32x4 ag[3] = {f32x4{0}, f32x4{0}, f32x4{0}};
        __builtin_amdgcn_s_setprio(1);
        {
            WAITN(6);
            short8 hh = __builtin_bit_cast(short8, hf[0]);
            short8 hl = __builtin_bit_cast(short8, hf[1]);
#pragma unroll
            for (int nt = 0; nt < 3; ++nt) {
                ag[nt] = __builtin_amdgcn_mfma_f32_16x16x32_bf16(hh, bhh[nt][0], ag[nt], 0, 0, 0);
                ag[nt] = __builtin_amdgcn_mfma_f32_16x16x32_bf16(hl, bhh[nt][0], ag[nt], 0, 0, 0);
                ag[nt] = __builtin_amdgcn_mfma_f32_16x16x32_bf16(hh, bhl[nt][0], ag[nt], 0, 0, 0);
            }
        }
        {
            WAITN(4);
            short8 hh = __builtin_bit_cast(short8, hf[2]);
            short8 hl = __builtin_bit_cast(short8, hf[3]);
#pragma unroll
            for (int nt = 0; nt < 3; ++nt) {
                ag[nt] = __builtin_amdgcn_mfma_f32_16x16x32_bf16(hh, bhh[nt][1], ag[nt], 0, 0, 0);
                ag[nt] = __builtin_amdgcn_mfma_f32_16x16x32_bf16(hl, bhh[nt][1], ag[nt], 0, 0, 0);
                ag[nt] = __builtin_amdgcn_mfma_f32_16x16x32_bf16(hh, bhl[nt][1], ag[nt], 0, 0, 0);
            }
        }
        {
            WAITN(2);
            short8 hh = __builtin_bit_cast(short8, hf[4]);
            short8 hl = __builtin_bit_cast(short8, hf[5]);
#pragma unroll
            for (int nt = 0; nt < 3; ++nt) {
                ag[nt] = __builtin_amdgcn_mfma_f32_16x16x32_bf16(hh, bhh[nt][2], ag[nt], 0, 0, 0);
                ag[nt] = __builtin_amdgcn_mfma_f32_16x16x32_bf16(hl, bhh[nt][2], ag[nt], 0, 0, 0);
                ag[nt] = __builtin_amdgcn_mfma_f32_16x16x32_bf16(hh, bhl[nt][2], ag[nt], 0, 0, 0);
            }
        }
        {
            WAITN(0);
            short8 hh = __builtin_bit_cast(short8, hf[6]);
            short8 hl = __builtin_bit_cast(short8, hf[7]);
#pragma unroll
            for (int nt = 0; nt < 3; ++nt) {
                ag[nt] = __builtin_amdgcn_mfma_f32_16x16x32_bf16(hh, bhh[nt][3], ag[nt], 0, 0, 0);
                ag[nt] = __builtin_amdgcn_mfma_f32_16x16x32_bf16(hl, bhh[nt][3], ag[nt], 0, 0, 0);
                ag[nt] = __builtin_amdgcn_mfma_f32_16x16x32_bf16(hh, bhl[nt][3], ag[nt], 0, 0, 0);
            }
        }
        __builtin_amdgcn_s_setprio(0);

        // (f) publish both partial sets, one sync, combined reduce
#pragma unroll
        for (int s = 0; s < 3; ++s)
#pragma unroll
            for (int i = 0; i < 4; ++i) {
                pgi[kw][s][lrow][prow + i] = ai[s][i];
                pgh[kw][s][lrow][prow + i] = ag[s][i];
            }
        __syncthreads();

        // (g) epilogue (waves 0-3): gates, deferred out(t-1), premasked h(t+1)
        if (tid < 256) {
            float g0 = 0.f, g1 = 0.f, g2 = 0.f, h0 = 0.f, h1 = 0.f, h2 = 0.f;
#pragma unroll
            for (int k = 0; k < 8; ++k) {
                g0 += pgi[k][0][ej][eb];
                g1 += pgi[k][1][ej][eb];
                g2 += pgi[k][2][ej][eb];
                h0 += pgh[k][0][ej][eb];
                h1 += pgh[k][1][ej][eb];
                h2 += pgh[k][2][ej][eb];
            }
            float r = 1.f / (1.f + __expf(-(g0 + bi_r + h0)));
            float z = 1.f / (1.f + __expf(-(g1 + bi_z + h1)));
            float pre = g2 + bi_n + r * (h2 + bh_n);
            float e2 = __expf(2.f * pre);
            float n = 1.f - 2.f / (e2 + 1.f);
            float hnew = (1.f - z) * n + z * h_local;

            if (t) out[(size_t)(t - 1) * 65536u + brow * DD + ce] = ys_prev;
            ys_prev = hnew;

            if (t < TT - 1) {
                float heff = (rsv != 0u) ? 0.f : hnew;   // rsv drained by WAITN(0)
                h_local = heff;
                unsigned short ph = f2bf(heff);
                unsigned short pl = f2bf(heff - bf2f(ph));
                __hip_atomic_store(h_hi[cur ^ 1] + brow * DD + ce, ph,
                                   __ATOMIC_RELAXED, __HIP_MEMORY_SCOPE_AGENT);
                __hip_atomic_store(h_lo[cur ^ 1] + brow * DD + ce, pl,
                                   __ATOMIC_RELAXED, __HIP_MEMORY_SCOPE_AGENT);
            }
        }

        // (h) producer waves drain own stores; WG-wide sync; ONE arrival per WG
        if (kw < 4) vm0();
        __syncthreads();
        if (tid == 0 && t < TT - 1)
            __hip_atomic_fetch_add(rep, 1u, __ATOMIC_RELAXED, __HIP_MEMORY_SCOPE_AGENT);

        // (i) issue x(t+1) loads; they drain under the next poll
        if (t < TT - 1) {
            const unsigned* xpl = outw + (size_t)(t + 1) * 65536u;
#pragma unroll
            for (int kt = 0; kt < 4; ++kt) {
                ld16(xf[2 * kt],     xpl + xwbase + kt * 16);
                ld16(xf[2 * kt + 1], xpl + xwbase + 8192u + kt * 16);
            }
        }
    }

    if (tid < 256)
        out[(size_t)(TT - 1) * 65536u + brow * DD + ce] = ys_prev;
}

extern "C" void kernel_launch(void* const* d_in, const int* in_sizes, int n_in,
                              void* d_out, int out_size, void* d_ws, size_t ws_size,
                              hipStream_t stream) {
    const float* x = (const float*)d_in[0];
    const float* Wi = (const float*)d_in[1];
    const float* bi = (const float*)d_in[2];
    const float* Wh = (const float*)d_in[3];
    const float* bhn = (const float*)d_in[4];
    const unsigned char* resets = (const unsigned char*)d_in[5];
    float* out = (float*)d_out;
    unsigned char* ws = (unsigned char*)d_ws;

    if (ws_size < WS_NEED) return;

    hipLaunchKernelGGL(pack_x_kernel, dim3(16384), dim3(256), 0, stream, x, (unsigned*)out);
    hipLaunchKernelGGL(prep_kernel, dim3(257), dim3(256), 0, stream, resets, ws);

    void* args[] = {(void*)&Wi, (void*)&bi, (void*)&Wh, (void*)&bhn,
                    (void*)&resets, (void*)&out, (void*)&ws};
    hipError_t err = hipLaunchCooperativeKernel((const void*)gru_kernel, dim3(256), dim3(512),
                                                args, 0, stream);
    if (err != hipSuccess) {
        hipLaunchKernelGGL(gru_kernel, dim3(256), dim3(512), 0, stream,
                           Wi, bi, Wh, bhn, resets, out, ws);
    }
}

// Round 11
// 2651.751 us; speedup vs baseline: 2.0106x; 1.2383x over previous
//
#include <hip/hip_runtime.h>

// GRU scan, T=512 B=64 D=1024. Persistent cooperative kernel.
// R6-proven skeleton: 256 WGs = 4 mgrps x 64 col-WGs; 512 thr (8 waves, K 128/wave);
// per-PRODUCER-WAVE arrivals (4 independent fetch_adds/WG to 8 replica lines),
// all-wave wave-uniform 8-replica poll, gi(t+1) in post-arrive tail.
// R11 fix (one variable vs R6): x(t+1) issued AFTER epilogue stores; producer
// arrive-drain is WAITN(8) (drains the 3 stores only, x stays in flight) instead
// of vm0 (which waited for x L3 latency on the arrive path). h-load waits 6/4/2/0.

typedef __attribute__((ext_vector_type(8))) short short8;
typedef __attribute__((ext_vector_type(4))) float f32x4;
typedef __attribute__((ext_vector_type(4))) unsigned int u32x4;

#define DEV static __device__ __forceinline__

constexpr int TT = 512, BB = 64, DD = 1024, TD = 3072;

constexpr size_t WS_BAR = 256;                 // barrier area: 4 mgrps x 256 words
constexpr size_t WS_H = 8192;                  // h planes: hb0_hi, hb0_lo, hb1_hi, hb1_lo
constexpr size_t HPLANE = (size_t)BB * DD * 2; // 128 KB per plane
constexpr size_t WS_NEED = WS_H + 4 * HPLANE;

DEV unsigned short f2bf(float f) {   // RNE float->bf16
    unsigned u = __builtin_bit_cast(unsigned, f);
    u += 0x7FFFu + ((u >> 16) & 1u);
    return (unsigned short)(u >> 16);
}
DEV float bf2f(unsigned short s) { return __builtin_bit_cast(float, ((unsigned)s) << 16); }

DEV void ld16c(u32x4& r, const unsigned* p) {   // coherent 16B load (L1+L2 bypass)
    asm volatile("global_load_dwordx4 %0, %1, off sc0 sc1" : "=v"(r) : "v"(p));
}
DEV void ld16(u32x4& r, const unsigned* p) {    // plain cached 16B load
    asm volatile("global_load_dwordx4 %0, %1, off" : "=v"(r) : "v"(p));
}
DEV void ld8u(unsigned& r, const unsigned char* p) {
    asm volatile("global_load_ubyte %0, %1, off" : "=v"(r) : "v"(p));
}
DEV void vm0() {
    asm volatile("s_waitcnt vmcnt(0)" ::: "memory");
    __builtin_amdgcn_sched_barrier(0);   // rule #18
}
#define WAITN(n) do { asm volatile("s_waitcnt vmcnt(" #n ")" ::: "memory"); \
                      __builtin_amdgcn_sched_barrier(0); } while (0)

// ---------------- prepass A: split x into bf16 hi/lo planes, MGRP-LOCAL layout ----------------
// plane t (65536 words): mgrp m: words [m*16384, +8192) = x_hi rows m*16..+16,
//                        words [m*16384+8192, +8192) = x_lo same rows.
__global__ void pack_x_kernel(const float* __restrict__ x, unsigned* __restrict__ outw) {
    const size_t gid = (size_t)blockIdx.x * 256 + threadIdx.x;
    const size_t e0 = gid * 8;
    const unsigned t = (unsigned)(e0 >> 16);
    const unsigned p = (unsigned)(e0 & 65535u);
    const unsigned r = p >> 10, d = p & 1023u;
    const unsigned m = r >> 4, lr = r & 15u;
    f32x4 a = *(const f32x4*)(x + e0);
    f32x4 b = *(const f32x4*)(x + e0 + 4);
    u32x4 wh, wl;
#pragma unroll
    for (int j = 0; j < 2; ++j) {
        unsigned short h0 = f2bf(a[2 * j]), h1 = f2bf(a[2 * j + 1]);
        wh[j] = (unsigned)h0 | ((unsigned)h1 << 16);
        wl[j] = (unsigned)f2bf(a[2 * j] - bf2f(h0)) | ((unsigned)f2bf(a[2 * j + 1] - bf2f(h1)) << 16);
        unsigned short g0 = f2bf(b[2 * j]), g1 = f2bf(b[2 * j + 1]);
        wh[2 + j] = (unsigned)g0 | ((unsigned)g1 << 16);
        wl[2 + j] = (unsigned)f2bf(b[2 * j] - bf2f(g0)) | ((unsigned)f2bf(b[2 * j + 1] - bf2f(g1)) << 16);
    }
    unsigned* base = outw + (size_t)t * 65536u + m * 16384u + ((lr * 1024u + d) >> 1);
    *(u32x4*)base = wh;
    *(u32x4*)(base + 8192u) = wl;
}

// ---------------- prepass B: zero h-buf0 + barrier area, detect resets stride ----------------
__global__ void prep_kernel(const unsigned char* __restrict__ resets, unsigned char* __restrict__ ws) {
    const int bid = blockIdx.x, tid = threadIdx.x;
    if (bid < 256) {
        ((unsigned*)(ws + WS_H))[bid * 256 + tid] = 0u;   // zero hb0 hi+lo (256 KB)
    } else {
        unsigned* w32 = (unsigned*)ws;
        for (int i = tid; i < 2048; i += 256) w32[i] = 0u;
        __shared__ int ca, cb, cc;
        if (tid == 0) { ca = 0; cb = 0; cc = 0; }
        __syncthreads();
        int la = 0, lb = 0, lc = 0;
        for (int o = tid * 16; o < tid * 16 + 16; ++o) {
            unsigned char v = resets[o];
            if (v) {
                if ((o & 3) == 0) la = 1; else lb = 1;
                if ((o & 7) == 4) lc = 1;
            }
        }
        if (la) atomicOr(&ca, 1);
        if (lb) atomicOr(&cb, 1);
        if (lc) atomicOr(&cc, 1);
        __syncthreads();
        if (tid == 0) {
            unsigned stride, boff = 0;
            if (ca && cb)       { stride = 1; }
            else if (!ca && cb) { stride = 4; boff = 3; }
            else if (ca && cc)  { stride = 4; }
            else if (ca)        { stride = 8; }
            else                { stride = 4; }
            w32[0] = stride; w32[1] = boff;
        }
    }
}

// ---------------- main persistent kernel ----------------
__launch_bounds__(512, 1)
__global__ void gru_kernel(const float* __restrict__ Wi, const float* __restrict__ bi,
                           const float* __restrict__ Wh, const float* __restrict__ bhn,
                           const unsigned char* __restrict__ resets,
                           float* __restrict__ out, unsigned char* __restrict__ ws) {
    const int tid = threadIdx.x;
    const int wg = blockIdx.x;
    const int lane = tid & 63;
    const int kw = tid >> 6;
    const int mgrp = wg >> 6;
    const int cg = wg & 63;
    const int c0 = cg * 16;

    unsigned* bar = (unsigned*)(ws + WS_BAR) + mgrp * 256;   // 8 replicas at r*32 words
    unsigned* rep = &bar[((cg * 4 + kw) & 7) * 32];
    const unsigned rstride = ((const unsigned*)ws)[0];
    const unsigned rboff   = ((const unsigned*)ws)[1];

    unsigned short* h_hi[2] = {(unsigned short*)(ws + WS_H),
                               (unsigned short*)(ws + WS_H + 2 * HPLANE)};
    unsigned short* h_lo[2] = {(unsigned short*)(ws + WS_H + HPLANE),
                               (unsigned short*)(ws + WS_H + 3 * HPLANE)};
    unsigned* outw = (unsigned*)out;

    const int lrow = lane & 15;
    const int lk = (lane >> 4) * 8;

    // ---- persistent B fragments (Wi_hi, Wh_hi, Wh_lo) ----
    short8 bih[3][4], bhh[3][4], bhl[3][4];
#pragma unroll
    for (int nt = 0; nt < 3; ++nt) {
        const int col = nt * DD + c0 + lrow;
#pragma unroll
        for (int kt = 0; kt < 4; ++kt) {
            const int kb = kw * 128 + kt * 32 + lk;
            short8 a, c, d;
#pragma unroll
            for (int j = 0; j < 8; ++j) {
                float wi = Wi[(size_t)(kb + j) * TD + col];
                a[j] = (short)f2bf(wi);
                float wh = Wh[(size_t)(kb + j) * TD + col];
                unsigned short h2 = f2bf(wh);
                c[j] = (short)h2;
                d[j] = (short)f2bf(wh - bf2f(h2));
            }
            bih[nt][kt] = a; bhh[nt][kt] = c; bhl[nt][kt] = d;
        }
    }

    // ---- epilogue constants ----
    const int eb = (tid & 255) >> 4, ej = tid & 15;
    const int brow = mgrp * 16 + eb;
    const int ce = c0 + ej;
    const float bi_r = bi[ce], bi_z = bi[DD + ce], bi_n = bi[2 * DD + ce];
    const float bh_n = bhn[ce];
    float h_local = 0.f;
    float ys_prev = 0.f;

    const unsigned xlidx = (unsigned)(lrow * 1024 + kw * 128 + lk);
    const unsigned xwbase = (unsigned)mgrp * 16384u + (xlidx >> 1);
    const unsigned hidx = (unsigned)((mgrp * 16 + lrow) * 1024 + kw * 128 + lk);
    const size_t r64 = (size_t)64 * rstride;
    const size_t roffb = (size_t)brow * rstride + rboff;

    __shared__ float pgi[8][3][16][18];
    __shared__ float pgh[8][3][16][18];
    const int prow = (lane >> 4) * 4;

    // ================= prologue: gi(0) =================
    {
        const unsigned* xpl = outw;   // plane 0
        u32x4 xf0[8];
#pragma unroll
        for (int kt = 0; kt < 4; ++kt) {
            ld16(xf0[2 * kt],     xpl + xwbase + kt * 16);
            ld16(xf0[2 * kt + 1], xpl + xwbase + 8192u + kt * 16);
        }
        vm0();
        f32x4 ai[3] = {f32x4{0}, f32x4{0}, f32x4{0}};
#pragma unroll
        for (int kt = 0; kt < 4; ++kt) {
            short8 xh = __builtin_bit_cast(short8, xf0[2 * kt]);
            short8 xl = __builtin_bit_cast(short8, xf0[2 * kt + 1]);
#pragma unroll
            for (int nt = 0; nt < 3; ++nt)
                ai[nt] = __builtin_amdgcn_mfma_f32_16x16x32_bf16(xh, bih[nt][kt], ai[nt], 0, 0, 0);
#pragma unroll
            for (int nt = 0; nt < 3; ++nt)
                ai[nt] = __builtin_amdgcn_mfma_f32_16x16x32_bf16(xl, bih[nt][kt], ai[nt], 0, 0, 0);
        }
#pragma unroll
        for (int s = 0; s < 3; ++s)
#pragma unroll
            for (int i = 0; i < 4; ++i)
                pgi[kw][s][prow + i][lrow] = ai[s][i];
        __syncthreads();
    }

    // ================= main loop =================
    for (int t = 0; t < TT; ++t) {
        // (a) per-wave poll: 256 arrivals/step/mgrp (wave-uniform atomic loads)
        if (t) {
            const unsigned target = 256u * (unsigned)t;
            int guard = 1 << 20;       // bounded spin: fail loud, never hang
            unsigned s;
            do {
                s = 0;
#pragma unroll
                for (int r2 = 0; r2 < 8; ++r2)
                    s += __hip_atomic_load(&bar[r2 * 32], __ATOMIC_RELAXED, __HIP_MEMORY_SCOPE_AGENT);
            } while (s < target && --guard);
        }
        __builtin_amdgcn_sched_barrier(0);

        const int tn = (t + 1 < TT) ? (t + 1) : (TT - 1);

        // (b) issue: rsv byte + coherent h(t) loads  (queue: [rsv][h8] = 9)
        unsigned rsv;
        ld8u(rsv, resets + roffb + (size_t)tn * r64);
        const int cur = t & 1;
        const unsigned* hhp = (const unsigned*)h_hi[cur];
        const unsigned* hlp = (const unsigned*)h_lo[cur];
        u32x4 hf[8];
#pragma unroll
        for (int kt = 0; kt < 4; ++kt) {
            ld16c(hf[2 * kt],     hhp + ((hidx + kt * 32) >> 1));
            ld16c(hf[2 * kt + 1], hlp + ((hidx + kt * 32) >> 1));
        }

        // (c) gi reduce (LDS only, hides h latency)
        float g0 = 0.f, g1 = 0.f, g2 = 0.f;
        if (tid < 256) {
#pragma unroll
            for (int k = 0; k < 8; ++k) {
                g0 += pgi[k][0][eb][ej];
                g1 += pgi[k][1][eb][ej];
                g2 += pgi[k][2][eb][ej];
            }
        }

        // (d) gh MFMAs, counted waits per k-tile
        f32x4 ag[3] = {f32x4{0}, f32x4{0}, f32x4{0}};
        __builtin_amdgcn_s_setprio(1);
        {
            WAITN(6);
            short8 hh = __builtin_bit_cast(short8, hf[0]);
            short8 hl = __builtin_bit_cast(short8, hf[1]);
#pragma unroll
            for (int nt = 0; nt < 3; ++nt) {
                ag[nt] = __builtin_amdgcn_mfma_f32_16x16x32_bf16(hh, bhh[nt][0], ag[nt], 0, 0, 0);
                ag[nt] = __builtin_amdgcn_mfma_f32_16x16x32_bf16(hl, bhh[nt][0], ag[nt], 0, 0, 0);
                ag[nt] = __builtin_amdgcn_mfma_f32_16x16x32_bf16(hh, bhl[nt][0], ag[nt], 0, 0, 0);
            }
        }
        {
            WAITN(4);
            short8 hh = __builtin_bit_cast(short8, hf[2]);
            short8 hl = __builtin_bit_cast(short8, hf[3]);
#pragma unroll
            for (int nt = 0; nt < 3; ++nt) {
                ag[nt] = __builtin_amdgcn_mfma_f32_16x16x32_bf16(hh, bhh[nt][1], ag[nt], 0, 0, 0);
                ag[nt] = __builtin_amdgcn_mfma_f32_16x16x32_bf16(hl, bhh[nt][1], ag[nt], 0, 0, 0);
                ag[nt] = __builtin_amdgcn_mfma_f32_16x16x32_bf16(hh, bhl[nt][1], ag[nt], 0, 0, 0);
            }
        }
        {
            WAITN(2);
            short8 hh = __builtin_bit_cast(short8, hf[4]);
            short8 hl = __builtin_bit_cast(short8, hf[5]);
#pragma unroll
            for (int nt = 0; nt < 3; ++nt) {
                ag[nt] = __builtin_amdgcn_mfma_f32_16x16x32_bf16(hh, bhh[nt][2], ag[nt], 0, 0, 0);
                ag[nt] = __builtin_amdgcn_mfma_f32_16x16x32_bf16(hl, bhh[nt][2], ag[nt], 0, 0, 0);
                ag[nt] = __builtin_amdgcn_mfma_f32_16x16x32_bf16(hh, bhl[nt][2], ag[nt], 0, 0, 0);
            }
        }
        {
            WAITN(0);
            short8 hh = __builtin_bit_cast(short8, hf[6]);
            short8 hl = __builtin_bit_cast(short8, hf[7]);
#pragma unroll
            for (int nt = 0; nt < 3; ++nt) {
                ag[nt] = __builtin_amdgcn_mfma_f32_16x16x32_bf16(hh, bhh[nt][3], ag[nt], 0, 0, 0);
                ag[nt] = __builtin_amdgcn_mfma_f32_16x16x32_bf16(hl, bhh[nt][3], ag[nt], 0, 0, 0);
                ag[nt] = __builtin_amdgcn_mfma_f32_16x16x32_bf16(hh, bhl[nt][3], ag[nt], 0, 0, 0);
            }
        }
        __builtin_amdgcn_s_setprio(0);

        // (e) publish gh partials
#pragma unroll
        for (int s = 0; s < 3; ++s)
#pragma unroll
            for (int i = 0; i < 4; ++i)
                pgh[kw][s][prow + i][lrow] = ag[s][i];
        __syncthreads();

        // (f) epilogue (waves 0-3): gates, deferred out(t-1), premasked h(t+1)
        if (tid < 256) {
            float h0 = 0.f, h1 = 0.f, h2 = 0.f;
#pragma unroll
            for (int k = 0; k < 8; ++k) {
                h0 += pgh[k][0][eb][ej];
                h1 += pgh[k][1][eb][ej];
                h2 += pgh[k][2][eb][ej];
            }
            float r = 1.f / (1.f + __expf(-(g0 + bi_r + h0)));
            float z = 1.f / (1.f + __expf(-(g1 + bi_z + h1)));
            float pre = g2 + bi_n + r * (h2 + bh_n);
            float e2 = __expf(2.f * pre);
            float n = 1.f - 2.f / (e2 + 1.f);
            float hnew = (1.f - z) * n + z * h_local;

            if (t) out[(size_t)(t - 1) * 65536u + brow * DD + ce] = ys_prev;
            ys_prev = hnew;

            if (t < TT - 1) {
                float heff = (rsv != 0u) ? 0.f : hnew;   // rsv drained by WAITN(6)
                h_local = heff;
                unsigned short ph = f2bf(heff);
                unsigned short pl = f2bf(heff - bf2f(ph));
                __hip_atomic_store(h_hi[cur ^ 1] + brow * DD + ce, ph,
                                   __ATOMIC_RELAXED, __HIP_MEMORY_SCOPE_AGENT);
                __hip_atomic_store(h_lo[cur ^ 1] + brow * DD + ce, pl,
                                   __ATOMIC_RELAXED, __HIP_MEMORY_SCOPE_AGENT);
            }
        }
        asm volatile("" ::: "memory");   // pin store -> x-issue program order

        // (g) issue x(t+1) AFTER stores (drains under next poll, off arrive path)
        u32x4 xf[8];
        if (t < TT - 1) {
            const unsigned* xpl = outw + (size_t)(t + 1) * 65536u;
#pragma unroll
            for (int kt = 0; kt < 4; ++kt) {
                ld16(xf[2 * kt],     xpl + xwbase + kt * 16);
                ld16(xf[2 * kt + 1], xpl + xwbase + 8192u + kt * 16);
            }
        }

        // (h) producer waves: drain ONLY the 3 stores (oldest; x stays in flight),
        //     then arrive independently (4 replicas per WG, no syncthreads).
        if (kw < 4) {
            WAITN(8);
            if (lane == 0 && t < TT - 1)
                __hip_atomic_fetch_add(rep, 1u, __ATOMIC_RELAXED, __HIP_MEMORY_SCOPE_AGENT);
        }

        // (i) tail: drain x, gi(t+1) MFMAs, publish, sync
        if (t < TT - 1) {
            WAITN(0);
            f32x4 ai[3] = {f32x4{0}, f32x4{0}, f32x4{0}};
#pragma unroll
            for (int kt = 0; kt < 4; ++kt) {
                short8 xh = __builtin_bit_cast(short8, xf[2 * kt]);
                short8 xl = __builtin_bit_cast(short8, xf[2 * kt + 1]);
#pragma unroll
                for (int nt = 0; nt < 3; ++nt)
                    ai[nt] = __builtin_amdgcn_mfma_f32_16x16x32_bf16(xh, bih[nt][kt], ai[nt], 0, 0, 0);
#pragma unroll
                for (int nt = 0; nt < 3; ++nt)
                    ai[nt] = __builtin_amdgcn_mfma_f32_16x16x32_bf16(xl, bih[nt][kt], ai[nt], 0, 0, 0);
            }
#pragma unroll
            for (int s = 0; s < 3; ++s)
#pragma unroll
                for (int i = 0; i < 4; ++i)
                    pgi[kw][s][prow + i][lrow] = ai[s][i];
            __syncthreads();
        }
    }

    if (tid < 256)
        out[(size_t)(TT - 1) * 65536u + brow * DD + ce] = ys_prev;
}

extern "C" void kernel_launch(void* const* d_in, const int* in_sizes, int n_in,
                              void* d_out, int out_size, void* d_ws, size_t ws_size,
                              hipStream_t stream) {
    const float* x = (const float*)d_in[0];
    const float* Wi = (const float*)d_in[1];
    const float* bi = (const float*)d_in[2];
    const float* Wh = (const float*)d_in[3];
    const float* bhn = (const float*)d_in[4];
    const unsigned char* resets = (const unsigned char*)d_in[5];
    float* out = (float*)d_out;
    unsigned char* ws = (unsigned char*)d_ws;

    if (ws_size < WS_NEED) return;

    hipLaunchKernelGGL(pack_x_kernel, dim3(16384), dim3(256), 0, stream, x, (unsigned*)out);
    hipLaunchKernelGGL(prep_kernel, dim3(257), dim3(256), 0, stream, resets, ws);

    void* args[] = {(void*)&Wi, (void*)&bi, (void*)&Wh, (void*)&bhn,
                    (void*)&resets, (void*)&out, (void*)&ws};
    hipError_t err = hipLaunchCooperativeKernel((const void*)gru_kernel, dim3(256), dim3(512),
                                                args, 0, stream);
    if (err != hipSuccess) {
        hipLaunchKernelGGL(gru_kernel, dim3(256), dim3(512), 0, stream,
                           Wi, bi, Wh, bhn, resets, out, ws);
    }
}

// Round 12
// 2633.555 us; speedup vs baseline: 2.0245x; 1.0069x over previous
//
#include <hip/hip_runtime.h>

// GRU scan, T=512 B=64 D=1024. Persistent cooperative kernel.
// R11 skeleton: 256 WGs = 4 mgrps x 64 col-WGs; 512 thr (8 waves, K 128/wave);
// weights persistent in registers; x pre-split to bf16 hi/lo planes in d_out;
// out(t-1) deferred; x(t+1) issued after stores; producer arrive after WAITN(8).
// R12 change (ONE variable): OCTET-SPLIT barrier. Wave kw's K-slice (h columns
// [kw*128,+128)) is produced by the 8 WGs cg in [8kw,8kw+8) only. 8 counters
// per mgrp (one per octet); WG cg's 4 producer waves arrive at counter[cg>>3];
// wave kw polls ONLY counter[kw] >= 32*t (single wave-uniform atomic load).
// Waves start gh as soon as their own octet is ready (de-jitters the mgrp).

typedef __attribute__((ext_vector_type(8))) short short8;
typedef __attribute__((ext_vector_type(4))) float f32x4;
typedef __attribute__((ext_vector_type(4))) unsigned int u32x4;

#define DEV static __device__ __forceinline__

constexpr int TT = 512, BB = 64, DD = 1024, TD = 3072;

constexpr size_t WS_BAR = 256;                 // barrier area: 4 mgrps x 256 words
constexpr size_t WS_H = 8192;                  // h planes: hb0_hi, hb0_lo, hb1_hi, hb1_lo
constexpr size_t HPLANE = (size_t)BB * DD * 2; // 128 KB per plane
constexpr size_t WS_NEED = WS_H + 4 * HPLANE;

DEV unsigned short f2bf(float f) {   // RNE float->bf16
    unsigned u = __builtin_bit_cast(unsigned, f);
    u += 0x7FFFu + ((u >> 16) & 1u);
    return (unsigned short)(u >> 16);
}
DEV float bf2f(unsigned short s) { return __builtin_bit_cast(float, ((unsigned)s) << 16); }

DEV void ld16c(u32x4& r, const unsigned* p) {   // coherent 16B load (L1+L2 bypass)
    asm volatile("global_load_dwordx4 %0, %1, off sc0 sc1" : "=v"(r) : "v"(p));
}
DEV void ld16(u32x4& r, const unsigned* p) {    // plain cached 16B load
    asm volatile("global_load_dwordx4 %0, %1, off" : "=v"(r) : "v"(p));
}
DEV void ld8u(unsigned& r, const unsigned char* p) {
    asm volatile("global_load_ubyte %0, %1, off" : "=v"(r) : "v"(p));
}
DEV void vm0() {
    asm volatile("s_waitcnt vmcnt(0)" ::: "memory");
    __builtin_amdgcn_sched_barrier(0);   // rule #18
}
#define WAITN(n) do { asm volatile("s_waitcnt vmcnt(" #n ")" ::: "memory"); \
                      __builtin_amdgcn_sched_barrier(0); } while (0)

// ---------------- prepass A: split x into bf16 hi/lo planes, MGRP-LOCAL layout ----------------
// plane t (65536 words): mgrp m: words [m*16384, +8192) = x_hi rows m*16..+16,
//                        words [m*16384+8192, +8192) = x_lo same rows.
__global__ void pack_x_kernel(const float* __restrict__ x, unsigned* __restrict__ outw) {
    const size_t gid = (size_t)blockIdx.x * 256 + threadIdx.x;
    const size_t e0 = gid * 8;
    const unsigned t = (unsigned)(e0 >> 16);
    const unsigned p = (unsigned)(e0 & 65535u);
    const unsigned r = p >> 10, d = p & 1023u;
    const unsigned m = r >> 4, lr = r & 15u;
    f32x4 a = *(const f32x4*)(x + e0);
    f32x4 b = *(const f32x4*)(x + e0 + 4);
    u32x4 wh, wl;
#pragma unroll
    for (int j = 0; j < 2; ++j) {
        unsigned short h0 = f2bf(a[2 * j]), h1 = f2bf(a[2 * j + 1]);
        wh[j] = (unsigned)h0 | ((unsigned)h1 << 16);
        wl[j] = (unsigned)f2bf(a[2 * j] - bf2f(h0)) | ((unsigned)f2bf(a[2 * j + 1] - bf2f(h1)) << 16);
        unsigned short g0 = f2bf(b[2 * j]), g1 = f2bf(b[2 * j + 1]);
        wh[2 + j] = (unsigned)g0 | ((unsigned)g1 << 16);
        wl[2 + j] = (unsigned)f2bf(b[2 * j] - bf2f(g0)) | ((unsigned)f2bf(b[2 * j + 1] - bf2f(g1)) << 16);
    }
    unsigned* base = outw + (size_t)t * 65536u + m * 16384u + ((lr * 1024u + d) >> 1);
    *(u32x4*)base = wh;
    *(u32x4*)(base + 8192u) = wl;
}

// ---------------- prepass B: zero h-buf0 + barrier area, detect resets stride ----------------
__global__ void prep_kernel(const unsigned char* __restrict__ resets, unsigned char* __restrict__ ws) {
    const int bid = blockIdx.x, tid = threadIdx.x;
    if (bid < 256) {
        ((unsigned*)(ws + WS_H))[bid * 256 + tid] = 0u;   // zero hb0 hi+lo (256 KB)
    } else {
        unsigned* w32 = (unsigned*)ws;
        for (int i = tid; i < 2048; i += 256) w32[i] = 0u;
        __shared__ int ca, cb, cc;
        if (tid == 0) { ca = 0; cb = 0; cc = 0; }
        __syncthreads();
        int la = 0, lb = 0, lc = 0;
        for (int o = tid * 16; o < tid * 16 + 16; ++o) {
            unsigned char v = resets[o];
            if (v) {
                if ((o & 3) == 0) la = 1; else lb = 1;
                if ((o & 7) == 4) lc = 1;
            }
        }
        if (la) atomicOr(&ca, 1);
        if (lb) atomicOr(&cb, 1);
        if (lc) atomicOr(&cc, 1);
        __syncthreads();
        if (tid == 0) {
            unsigned stride, boff = 0;
            if (ca && cb)       { stride = 1; }
            else if (!ca && cb) { stride = 4; boff = 3; }
            else if (ca && cc)  { stride = 4; }
            else if (ca)        { stride = 8; }
            else                { stride = 4; }
            w32[0] = stride; w32[1] = boff;
        }
    }
}

// ---------------- main persistent kernel ----------------
__launch_bounds__(512, 1)
__global__ void gru_kernel(const float* __restrict__ Wi, const float* __restrict__ bi,
                           const float* __restrict__ Wh, const float* __restrict__ bhn,
                           const unsigned char* __restrict__ resets,
                           float* __restrict__ out, unsigned char* __restrict__ ws) {
    const int tid = threadIdx.x;
    const int wg = blockIdx.x;
    const int lane = tid & 63;
    const int kw = tid >> 6;
    const int mgrp = wg >> 6;
    const int cg = wg & 63;
    const int c0 = cg * 16;

    unsigned* bar = (unsigned*)(ws + WS_BAR) + mgrp * 256;   // 8 octet ctrs at o*32 words
    unsigned* myctr  = &bar[kw * 32];          // the counter THIS wave polls
    unsigned* arrctr = &bar[(cg >> 3) * 32];   // the counter this WG's producers bump
    const unsigned rstride = ((const unsigned*)ws)[0];
    const unsigned rboff   = ((const unsigned*)ws)[1];

    unsigned short* h_hi[2] = {(unsigned short*)(ws + WS_H),
                               (unsigned short*)(ws + WS_H + 2 * HPLANE)};
    unsigned short* h_lo[2] = {(unsigned short*)(ws + WS_H + HPLANE),
                               (unsigned short*)(ws + WS_H + 3 * HPLANE)};
    unsigned* outw = (unsigned*)out;

    const int lrow = lane & 15;
    const int lk = (lane >> 4) * 8;

    // ---- persistent B fragments (Wi_hi, Wh_hi, Wh_lo) ----
    short8 bih[3][4], bhh[3][4], bhl[3][4];
#pragma unroll
    for (int nt = 0; nt < 3; ++nt) {
        const int col = nt * DD + c0 + lrow;
#pragma unroll
        for (int kt = 0; kt < 4; ++kt) {
            const int kb = kw * 128 + kt * 32 + lk;
            short8 a, c, d;
#pragma unroll
            for (int j = 0; j < 8; ++j) {
                float wi = Wi[(size_t)(kb + j) * TD + col];
                a[j] = (short)f2bf(wi);
                float wh = Wh[(size_t)(kb + j) * TD + col];
                unsigned short h2 = f2bf(wh);
                c[j] = (short)h2;
                d[j] = (short)f2bf(wh - bf2f(h2));
            }
            bih[nt][kt] = a; bhh[nt][kt] = c; bhl[nt][kt] = d;
        }
    }

    // ---- epilogue constants ----
    const int eb = (tid & 255) >> 4, ej = tid & 15;
    const int brow = mgrp * 16 + eb;
    const int ce = c0 + ej;
    const float bi_r = bi[ce], bi_z = bi[DD + ce], bi_n = bi[2 * DD + ce];
    const float bh_n = bhn[ce];
    float h_local = 0.f;
    float ys_prev = 0.f;

    const unsigned xlidx = (unsigned)(lrow * 1024 + kw * 128 + lk);
    const unsigned xwbase = (unsigned)mgrp * 16384u + (xlidx >> 1);
    const unsigned hidx = (unsigned)((mgrp * 16 + lrow) * 1024 + kw * 128 + lk);
    const size_t r64 = (size_t)64 * rstride;
    const size_t roffb = (size_t)brow * rstride + rboff;

    __shared__ float pgi[8][3][16][18];
    __shared__ float pgh[8][3][16][18];
    const int prow = (lane >> 4) * 4;

    // ================= prologue: gi(0) =================
    {
        const unsigned* xpl = outw;   // plane 0
        u32x4 xf0[8];
#pragma unroll
        for (int kt = 0; kt < 4; ++kt) {
            ld16(xf0[2 * kt],     xpl + xwbase + kt * 16);
            ld16(xf0[2 * kt + 1], xpl + xwbase + 8192u + kt * 16);
        }
        vm0();
        f32x4 ai[3] = {f32x4{0}, f32x4{0}, f32x4{0}};
#pragma unroll
        for (int kt = 0; kt < 4; ++kt) {
            short8 xh = __builtin_bit_cast(short8, xf0[2 * kt]);
            short8 xl = __builtin_bit_cast(short8, xf0[2 * kt + 1]);
#pragma unroll
            for (int nt = 0; nt < 3; ++nt)
                ai[nt] = __builtin_amdgcn_mfma_f32_16x16x32_bf16(xh, bih[nt][kt], ai[nt], 0, 0, 0);
#pragma unroll
            for (int nt = 0; nt < 3; ++nt)
                ai[nt] = __builtin_amdgcn_mfma_f32_16x16x32_bf16(xl, bih[nt][kt], ai[nt], 0, 0, 0);
        }
#pragma unroll
        for (int s = 0; s < 3; ++s)
#pragma unroll
            for (int i = 0; i < 4; ++i)
                pgi[kw][s][prow + i][lrow] = ai[s][i];
        __syncthreads();
    }

    // ================= main loop =================
    for (int t = 0; t < TT; ++t) {
        // (a) per-wave OCTET poll: counter[kw] >= 32*t (one wave-uniform load)
        if (t) {
            const unsigned target = 32u * (unsigned)t;
            int guard = 1 << 20;       // bounded spin: fail loud, never hang
            unsigned s;
            do {
                s = __hip_atomic_load(myctr, __ATOMIC_RELAXED, __HIP_MEMORY_SCOPE_AGENT);
            } while (s < target && --guard);
        }
        __builtin_amdgcn_sched_barrier(0);

        const int tn = (t + 1 < TT) ? (t + 1) : (TT - 1);

        // (b) issue: rsv byte + coherent h(t) loads  (queue: [rsv][h8] = 9)
        unsigned rsv;
        ld8u(rsv, resets + roffb + (size_t)tn * r64);
        const int cur = t & 1;
        const unsigned* hhp = (const unsigned*)h_hi[cur];
        const unsigned* hlp = (const unsigned*)h_lo[cur];
        u32x4 hf[8];
#pragma unroll
        for (int kt = 0; kt < 4; ++kt) {
            ld16c(hf[2 * kt],     hhp + ((hidx + kt * 32) >> 1));
            ld16c(hf[2 * kt + 1], hlp + ((hidx + kt * 32) >> 1));
        }

        // (c) gi reduce (LDS only, hides h latency)
        float g0 = 0.f, g1 = 0.f, g2 = 0.f;
        if (tid < 256) {
#pragma unroll
            for (int k = 0; k < 8; ++k) {
                g0 += pgi[k][0][eb][ej];
                g1 += pgi[k][1][eb][ej];
                g2 += pgi[k][2][eb][ej];
            }
        }

        // (d) gh MFMAs, counted waits per k-tile
        f32x4 ag[3] = {f32x4{0}, f32x4{0}, f32x4{0}};
        __builtin_amdgcn_s_setprio(1);
        {
            WAITN(6);
            short8 hh = __builtin_bit_cast(short8, hf[0]);
            short8 hl = __builtin_bit_cast(short8, hf[1]);
#pragma unroll
            for (int nt = 0; nt < 3; ++nt) {
                ag[nt] = __builtin_amdgcn_mfma_f32_16x16x32_bf16(hh, bhh[nt][0], ag[nt], 0, 0, 0);
                ag[nt] = __builtin_amdgcn_mfma_f32_16x16x32_bf16(hl, bhh[nt][0], ag[nt], 0, 0, 0);
                ag[nt] = __builtin_amdgcn_mfma_f32_16x16x32_bf16(hh, bhl[nt][0], ag[nt], 0, 0, 0);
            }
        }
        {
            WAITN(4);
            short8 hh = __builtin_bit_cast(short8, hf[2]);
            short8 hl = __builtin_bit_cast(short8, hf[3]);
#pragma unroll
            for (int nt = 0; nt < 3; ++nt) {
                ag[nt] = __builtin_amdgcn_mfma_f32_16x16x32_bf16(hh, bhh[nt][1], ag[nt], 0, 0, 0);
                ag[nt] = __builtin_amdgcn_mfma_f32_16x16x32_bf16(hl, bhh[nt][1], ag[nt], 0, 0, 0);
                ag[nt] = __builtin_amdgcn_mfma_f32_16x16x32_bf16(hh, bhl[nt][1], ag[nt], 0, 0, 0);
            }
        }
        {
            WAITN(2);
            short8 hh = __builtin_bit_cast(short8, hf[4]);
            short8 hl = __builtin_bit_cast(short8, hf[5]);
#pragma unroll
            for (int nt = 0; nt < 3; ++nt) {
                ag[nt] = __builtin_amdgcn_mfma_f32_16x16x32_bf16(hh, bhh[nt][2], ag[nt], 0, 0, 0);
                ag[nt] = __builtin_amdgcn_mfma_f32_16x16x32_bf16(hl, bhh[nt][2], ag[nt], 0, 0, 0);
                ag[nt] = __builtin_amdgcn_mfma_f32_16x16x32_bf16(hh, bhl[nt][2], ag[nt], 0, 0, 0);
            }
        }
        {
            WAITN(0);
            short8 hh = __builtin_bit_cast(short8, hf[6]);
            short8 hl = __builtin_bit_cast(short8, hf[7]);
#pragma unroll
            for (int nt = 0; nt < 3; ++nt) {
                ag[nt] = __builtin_amdgcn_mfma_f32_16x16x32_bf16(hh, bhh[nt][3], ag[nt], 0, 0, 0);
                ag[nt] = __builtin_amdgcn_mfma_f32_16x16x32_bf16(hl, bhh[nt][3], ag[nt], 0, 0, 0);
                ag[nt] = __builtin_amdgcn_mfma_f32_16x16x32_bf16(hh, bhl[nt][3], ag[nt], 0, 0, 0);
            }
        }
        __builtin_amdgcn_s_setprio(0);

        // (e) publish gh partials
#pragma unroll
        for (int s = 0; s < 3; ++s)
#pragma unroll
            for (int i = 0; i < 4; ++i)
                pgh[kw][s][prow + i][lrow] = ag[s][i];
        __syncthreads();

        // (f) epilogue (waves 0-3): gates, deferred out(t-1), premasked h(t+1)
        if (tid < 256) {
            float h0 = 0.f, h1 = 0.f, h2 = 0.f;
#pragma unroll
            for (int k = 0; k < 8; ++k) {
                h0 += pgh[k][0][eb][ej];
                h1 += pgh[k][1][eb][ej];
                h2 += pgh[k][2][eb][ej];
            }
            float r = 1.f / (1.f + __expf(-(g0 + bi_r + h0)));
            float z = 1.f / (1.f + __expf(-(g1 + bi_z + h1)));
            float pre = g2 + bi_n + r * (h2 + bh_n);
            float e2 = __expf(2.f * pre);
            float n = 1.f - 2.f / (e2 + 1.f);
            float hnew = (1.f - z) * n + z * h_local;

            if (t) out[(size_t)(t - 1) * 65536u + brow * DD + ce] = ys_prev;
            ys_prev = hnew;

            if (t < TT - 1) {
                float heff = (rsv != 0u) ? 0.f : hnew;   // rsv drained by WAITN(6)
                h_local = heff;
                unsigned short ph = f2bf(heff);
                unsigned short pl = f2bf(heff - bf2f(ph));
                __hip_atomic_store(h_hi[cur ^ 1] + brow * DD + ce, ph,
                                   __ATOMIC_RELAXED, __HIP_MEMORY_SCOPE_AGENT);
                __hip_atomic_store(h_lo[cur ^ 1] + brow * DD + ce, pl,
                                   __ATOMIC_RELAXED, __HIP_MEMORY_SCOPE_AGENT);
            }
        }
        asm volatile("" ::: "memory");   // pin store -> x-issue program order

        // (g) issue x(t+1) AFTER stores (drains under next poll, off arrive path)
        u32x4 xf[8];
        if (t < TT - 1) {
            const unsigned* xpl = outw + (size_t)(t + 1) * 65536u;
#pragma unroll
            for (int kt = 0; kt < 4; ++kt) {
                ld16(xf[2 * kt],     xpl + xwbase + kt * 16);
                ld16(xf[2 * kt + 1], xpl + xwbase + 8192u + kt * 16);
            }
        }

        // (h) producer waves: drain ONLY the stores (x stays in flight),
        //     arrive independently at this WG's OCTET counter.
        if (kw < 4) {
            WAITN(8);
            if (lane == 0 && t < TT - 1)
                __hip_atomic_fetch_add(arrctr, 1u, __ATOMIC_RELAXED, __HIP_MEMORY_SCOPE_AGENT);
        }

        // (i) tail: drain x, gi(t+1) MFMAs, publish, sync
        if (t < TT - 1) {
            WAITN(0);
            f32x4 ai[3] = {f32x4{0}, f32x4{0}, f32x4{0}};
#pragma unroll
            for (int kt = 0; kt < 4; ++kt) {
                short8 xh = __builtin_bit_cast(short8, xf[2 * kt]);
                short8 xl = __builtin_bit_cast(short8, xf[2 * kt + 1]);
#pragma unroll
                for (int nt = 0; nt < 3; ++nt)
                    ai[nt] = __builtin_amdgcn_mfma_f32_16x16x32_bf16(xh, bih[nt][kt], ai[nt], 0, 0, 0);
#pragma unroll
                for (int nt = 0; nt < 3; ++nt)
                    ai[nt] = __builtin_amdgcn_mfma_f32_16x16x32_bf16(xl, bih[nt][kt], ai[nt], 0, 0, 0);
            }
#pragma unroll
            for (int s = 0; s < 3; ++s)
#pragma unroll
                for (int i = 0; i < 4; ++i)
                    pgi[kw][s][prow + i][lrow] = ai[s][i];
            __syncthreads();
        }
    }

    if (tid < 256)
        out[(size_t)(TT - 1) * 65536u + brow * DD + ce] = ys_prev;
}

extern "C" void kernel_launch(void* const* d_in, const int* in_sizes, int n_in,
                              void* d_out, int out_size, void* d_ws, size_t ws_size,
                              hipStream_t stream) {
    const float* x = (const float*)d_in[0];
    const float* Wi = (const float*)d_in[1];
    const float* bi = (const float*)d_in[2];
    const float* Wh = (const float*)d_in[3];
    const float* bhn = (const float*)d_in[4];
    const unsigned char* resets = (const unsigned char*)d_in[5];
    float* out = (float*)d_out;
    unsigned char* ws = (unsigned char*)d_ws;

    if (ws_size < WS_NEED) return;

    hipLaunchKernelGGL(pack_x_kernel, dim3(16384), dim3(256), 0, stream, x, (unsigned*)out);
    hipLaunchKernelGGL(prep_kernel, dim3(257), dim3(256), 0, stream, resets, ws);

    void* args[] = {(void*)&Wi, (void*)&bi, (void*)&Wh, (void*)&bhn,
                    (void*)&resets, (void*)&out, (void*)&ws};
    hipError_t err = hipLaunchCooperativeKernel((const void*)gru_kernel, dim3(256), dim3(512),
                                                args, 0, stream);
    if (err != hipSuccess) {
        hipLaunchKernelGGL(gru_kernel, dim3(256), dim3(512), 0, stream,
                           Wi, bi, Wh, bhn, resets, out, ws);
    }
}

// Round 13
// 2621.539 us; speedup vs baseline: 2.0338x; 1.0046x over previous
//
#include <hip/hip_runtime.h>

// GRU scan, T=512 B=64 D=1024. Persistent cooperative kernel.
// R12 skeleton: 256 WGs = 4 mgrps x 64 col-WGs; 512 thr (8 waves, K 128/wave);
// weights persistent in registers; x pre-split to bf16 hi/lo planes in d_out;
// octet-split barrier (wave kw polls counter[kw] >= 32*t);
// out(t-1) deferred; x(t+1) issued after stores; producer drain = WAITN(8).
// R13 change (ONE variable): arrivals COALESCED per WG -- the 4 producer waves
// rendezvous on an LDS atomic (each after its own store-drain); the 4th wave
// issues a single global fetch_add(+4). Per-octet-line RMWs: 32 -> 8 per step
// (kills LLC same-address RMW serialization on the consumer-visible last arrival).

typedef __attribute__((ext_vector_type(8))) short short8;
typedef __attribute__((ext_vector_type(4))) float f32x4;
typedef __attribute__((ext_vector_type(4))) unsigned int u32x4;

#define DEV static __device__ __forceinline__

constexpr int TT = 512, BB = 64, DD = 1024, TD = 3072;

constexpr size_t WS_BAR = 256;                 // barrier area: 4 mgrps x 256 words
constexpr size_t WS_H = 8192;                  // h planes: hb0_hi, hb0_lo, hb1_hi, hb1_lo
constexpr size_t HPLANE = (size_t)BB * DD * 2; // 128 KB per plane
constexpr size_t WS_NEED = WS_H + 4 * HPLANE;

DEV unsigned short f2bf(float f) {   // RNE float->bf16
    unsigned u = __builtin_bit_cast(unsigned, f);
    u += 0x7FFFu + ((u >> 16) & 1u);
    return (unsigned short)(u >> 16);
}
DEV float bf2f(unsigned short s) { return __builtin_bit_cast(float, ((unsigned)s) << 16); }

DEV void ld16c(u32x4& r, const unsigned* p) {   // coherent 16B load (L1+L2 bypass)
    asm volatile("global_load_dwordx4 %0, %1, off sc0 sc1" : "=v"(r) : "v"(p));
}
DEV void ld16(u32x4& r, const unsigned* p) {    // plain cached 16B load
    asm volatile("global_load_dwordx4 %0, %1, off" : "=v"(r) : "v"(p));
}
DEV void ld8u(unsigned& r, const unsigned char* p) {
    asm volatile("global_load_ubyte %0, %1, off" : "=v"(r) : "v"(p));
}
DEV void vm0() {
    asm volatile("s_waitcnt vmcnt(0)" ::: "memory");
    __builtin_amdgcn_sched_barrier(0);   // rule #18
}
#define WAITN(n) do { asm volatile("s_waitcnt vmcnt(" #n ")" ::: "memory"); \
                      __builtin_amdgcn_sched_barrier(0); } while (0)

// ---------------- prepass A: split x into bf16 hi/lo planes, MGRP-LOCAL layout ----------------
// plane t (65536 words): mgrp m: words [m*16384, +8192) = x_hi rows m*16..+16,
//                        words [m*16384+8192, +8192) = x_lo same rows.
__global__ void pack_x_kernel(const float* __restrict__ x, unsigned* __restrict__ outw) {
    const size_t gid = (size_t)blockIdx.x * 256 + threadIdx.x;
    const size_t e0 = gid * 8;
    const unsigned t = (unsigned)(e0 >> 16);
    const unsigned p = (unsigned)(e0 & 65535u);
    const unsigned r = p >> 10, d = p & 1023u;
    const unsigned m = r >> 4, lr = r & 15u;
    f32x4 a = *(const f32x4*)(x + e0);
    f32x4 b = *(const f32x4*)(x + e0 + 4);
    u32x4 wh, wl;
#pragma unroll
    for (int j = 0; j < 2; ++j) {
        unsigned short h0 = f2bf(a[2 * j]), h1 = f2bf(a[2 * j + 1]);
        wh[j] = (unsigned)h0 | ((unsigned)h1 << 16);
        wl[j] = (unsigned)f2bf(a[2 * j] - bf2f(h0)) | ((unsigned)f2bf(a[2 * j + 1] - bf2f(h1)) << 16);
        unsigned short g0 = f2bf(b[2 * j]), g1 = f2bf(b[2 * j + 1]);
        wh[2 + j] = (unsigned)g0 | ((unsigned)g1 << 16);
        wl[2 + j] = (unsigned)f2bf(b[2 * j] - bf2f(g0)) | ((unsigned)f2bf(b[2 * j + 1] - bf2f(g1)) << 16);
    }
    unsigned* base = outw + (size_t)t * 65536u + m * 16384u + ((lr * 1024u + d) >> 1);
    *(u32x4*)base = wh;
    *(u32x4*)(base + 8192u) = wl;
}

// ---------------- prepass B: zero h-buf0 + barrier area, detect resets stride ----------------
__global__ void prep_kernel(const unsigned char* __restrict__ resets, unsigned char* __restrict__ ws) {
    const int bid = blockIdx.x, tid = threadIdx.x;
    if (bid < 256) {
        ((unsigned*)(ws + WS_H))[bid * 256 + tid] = 0u;   // zero hb0 hi+lo (256 KB)
    } else {
        unsigned* w32 = (unsigned*)ws;
        for (int i = tid; i < 2048; i += 256) w32[i] = 0u;
        __shared__ int ca, cb, cc;
        if (tid == 0) { ca = 0; cb = 0; cc = 0; }
        __syncthreads();
        int la = 0, lb = 0, lc = 0;
        for (int o = tid * 16; o < tid * 16 + 16; ++o) {
            unsigned char v = resets[o];
            if (v) {
                if ((o & 3) == 0) la = 1; else lb = 1;
                if ((o & 7) == 4) lc = 1;
            }
        }
        if (la) atomicOr(&ca, 1);
        if (lb) atomicOr(&cb, 1);
        if (lc) atomicOr(&cc, 1);
        __syncthreads();
        if (tid == 0) {
            unsigned stride, boff = 0;
            if (ca && cb)       { stride = 1; }
            else if (!ca && cb) { stride = 4; boff = 3; }
            else if (ca && cc)  { stride = 4; }
            else if (ca)        { stride = 8; }
            else                { stride = 4; }
            w32[0] = stride; w32[1] = boff;
        }
    }
}

// ---------------- main persistent kernel ----------------
__launch_bounds__(512, 1)
__global__ void gru_kernel(const float* __restrict__ Wi, const float* __restrict__ bi,
                           const float* __restrict__ Wh, const float* __restrict__ bhn,
                           const unsigned char* __restrict__ resets,
                           float* __restrict__ out, unsigned char* __restrict__ ws) {
    const int tid = threadIdx.x;
    const int wg = blockIdx.x;
    const int lane = tid & 63;
    const int kw = tid >> 6;
    const int mgrp = wg >> 6;
    const int cg = wg & 63;
    const int c0 = cg * 16;

    unsigned* bar = (unsigned*)(ws + WS_BAR) + mgrp * 256;   // 8 octet ctrs at o*32 words
    unsigned* myctr  = &bar[kw * 32];          // the counter THIS wave polls
    unsigned* arrctr = &bar[(cg >> 3) * 32];   // the counter this WG's producers bump
    const unsigned rstride = ((const unsigned*)ws)[0];
    const unsigned rboff   = ((const unsigned*)ws)[1];

    unsigned short* h_hi[2] = {(unsigned short*)(ws + WS_H),
                               (unsigned short*)(ws + WS_H + 2 * HPLANE)};
    unsigned short* h_lo[2] = {(unsigned short*)(ws + WS_H + HPLANE),
                               (unsigned short*)(ws + WS_H + 3 * HPLANE)};
    unsigned* outw = (unsigned*)out;

    const int lrow = lane & 15;
    const int lk = (lane >> 4) * 8;

    // ---- persistent B fragments (Wi_hi, Wh_hi, Wh_lo) ----
    short8 bih[3][4], bhh[3][4], bhl[3][4];
#pragma unroll
    for (int nt = 0; nt < 3; ++nt) {
        const int col = nt * DD + c0 + lrow;
#pragma unroll
        for (int kt = 0; kt < 4; ++kt) {
            const int kb = kw * 128 + kt * 32 + lk;
            short8 a, c, d;
#pragma unroll
            for (int j = 0; j < 8; ++j) {
                float wi = Wi[(size_t)(kb + j) * TD + col];
                a[j] = (short)f2bf(wi);
                float wh = Wh[(size_t)(kb + j) * TD + col];
                unsigned short h2 = f2bf(wh);
                c[j] = (short)h2;
                d[j] = (short)f2bf(wh - bf2f(h2));
            }
            bih[nt][kt] = a; bhh[nt][kt] = c; bhl[nt][kt] = d;
        }
    }

    // ---- epilogue constants ----
    const int eb = (tid & 255) >> 4, ej = tid & 15;
    const int brow = mgrp * 16 + eb;
    const int ce = c0 + ej;
    const float bi_r = bi[ce], bi_z = bi[DD + ce], bi_n = bi[2 * DD + ce];
    const float bh_n = bhn[ce];
    float h_local = 0.f;
    float ys_prev = 0.f;

    const unsigned xlidx = (unsigned)(lrow * 1024 + kw * 128 + lk);
    const unsigned xwbase = (unsigned)mgrp * 16384u + (xlidx >> 1);
    const unsigned hidx = (unsigned)((mgrp * 16 + lrow) * 1024 + kw * 128 + lk);
    const size_t r64 = (size_t)64 * rstride;
    const size_t roffb = (size_t)brow * rstride + rboff;

    __shared__ float pgi[8][3][16][18];
    __shared__ float pgh[8][3][16][18];
    __shared__ int wgarr;               // producer-wave rendezvous (monotonic)
    const int prow = (lane >> 4) * 4;

    // ================= prologue: gi(0) =================
    {
        if (tid == 0) wgarr = 0;
        const unsigned* xpl = outw;   // plane 0
        u32x4 xf0[8];
#pragma unroll
        for (int kt = 0; kt < 4; ++kt) {
            ld16(xf0[2 * kt],     xpl + xwbase + kt * 16);
            ld16(xf0[2 * kt + 1], xpl + xwbase + 8192u + kt * 16);
        }
        vm0();
        f32x4 ai[3] = {f32x4{0}, f32x4{0}, f32x4{0}};
#pragma unroll
        for (int kt = 0; kt < 4; ++kt) {
            short8 xh = __builtin_bit_cast(short8, xf0[2 * kt]);
            short8 xl = __builtin_bit_cast(short8, xf0[2 * kt + 1]);
#pragma unroll
            for (int nt = 0; nt < 3; ++nt)
                ai[nt] = __builtin_amdgcn_mfma_f32_16x16x32_bf16(xh, bih[nt][kt], ai[nt], 0, 0, 0);
#pragma unroll
            for (int nt = 0; nt < 3; ++nt)
                ai[nt] = __builtin_amdgcn_mfma_f32_16x16x32_bf16(xl, bih[nt][kt], ai[nt], 0, 0, 0);
        }
#pragma unroll
        for (int s = 0; s < 3; ++s)
#pragma unroll
            for (int i = 0; i < 4; ++i)
                pgi[kw][s][prow + i][lrow] = ai[s][i];
        __syncthreads();
    }

    // ================= main loop =================
    for (int t = 0; t < TT; ++t) {
        // (a) per-wave OCTET poll: counter[kw] >= 32*t (one wave-uniform load)
        if (t) {
            const unsigned target = 32u * (unsigned)t;
            int guard = 1 << 20;       // bounded spin: fail loud, never hang
            unsigned s;
            do {
                s = __hip_atomic_load(myctr, __ATOMIC_RELAXED, __HIP_MEMORY_SCOPE_AGENT);
            } while (s < target && --guard);
        }
        __builtin_amdgcn_sched_barrier(0);

        const int tn = (t + 1 < TT) ? (t + 1) : (TT - 1);

        // (b) issue: rsv byte + coherent h(t) loads  (queue: [rsv][h8] = 9)
        unsigned rsv;
        ld8u(rsv, resets + roffb + (size_t)tn * r64);
        const int cur = t & 1;
        const unsigned* hhp = (const unsigned*)h_hi[cur];
        const unsigned* hlp = (const unsigned*)h_lo[cur];
        u32x4 hf[8];
#pragma unroll
        for (int kt = 0; kt < 4; ++kt) {
            ld16c(hf[2 * kt],     hhp + ((hidx + kt * 32) >> 1));
            ld16c(hf[2 * kt + 1], hlp + ((hidx + kt * 32) >> 1));
        }

        // (c) gi reduce (LDS only, hides h latency)
        float g0 = 0.f, g1 = 0.f, g2 = 0.f;
        if (tid < 256) {
#pragma unroll
            for (int k = 0; k < 8; ++k) {
                g0 += pgi[k][0][eb][ej];
                g1 += pgi[k][1][eb][ej];
                g2 += pgi[k][2][eb][ej];
            }
        }

        // (d) gh MFMAs, counted waits per k-tile
        f32x4 ag[3] = {f32x4{0}, f32x4{0}, f32x4{0}};
        __builtin_amdgcn_s_setprio(1);
        {
            WAITN(6);
            short8 hh = __builtin_bit_cast(short8, hf[0]);
            short8 hl = __builtin_bit_cast(short8, hf[1]);
#pragma unroll
            for (int nt = 0; nt < 3; ++nt) {
                ag[nt] = __builtin_amdgcn_mfma_f32_16x16x32_bf16(hh, bhh[nt][0], ag[nt], 0, 0, 0);
                ag[nt] = __builtin_amdgcn_mfma_f32_16x16x32_bf16(hl, bhh[nt][0], ag[nt], 0, 0, 0);
                ag[nt] = __builtin_amdgcn_mfma_f32_16x16x32_bf16(hh, bhl[nt][0], ag[nt], 0, 0, 0);
            }
        }
        {
            WAITN(4);
            short8 hh = __builtin_bit_cast(short8, hf[2]);
            short8 hl = __builtin_bit_cast(short8, hf[3]);
#pragma unroll
            for (int nt = 0; nt < 3; ++nt) {
                ag[nt] = __builtin_amdgcn_mfma_f32_16x16x32_bf16(hh, bhh[nt][1], ag[nt], 0, 0, 0);
                ag[nt] = __builtin_amdgcn_mfma_f32_16x16x32_bf16(hl, bhh[nt][1], ag[nt], 0, 0, 0);
                ag[nt] = __builtin_amdgcn_mfma_f32_16x16x32_bf16(hh, bhl[nt][1], ag[nt], 0, 0, 0);
            }
        }
        {
            WAITN(2);
            short8 hh = __builtin_bit_cast(short8, hf[4]);
            short8 hl = __builtin_bit_cast(short8, hf[5]);
#pragma unroll
            for (int nt = 0; nt < 3; ++nt) {
                ag[nt] = __builtin_amdgcn_mfma_f32_16x16x32_bf16(hh, bhh[nt][2], ag[nt], 0, 0, 0);
                ag[nt] = __builtin_amdgcn_mfma_f32_16x16x32_bf16(hl, bhh[nt][2], ag[nt], 0, 0, 0);
                ag[nt] = __builtin_amdgcn_mfma_f32_16x16x32_bf16(hh, bhl[nt][2], ag[nt], 0, 0, 0);
            }
        }
        {
            WAITN(0);
            short8 hh = __builtin_bit_cast(short8, hf[6]);
            short8 hl = __builtin_bit_cast(short8, hf[7]);
#pragma unroll
            for (int nt = 0; nt < 3; ++nt) {
                ag[nt] = __builtin_amdgcn_mfma_f32_16x16x32_bf16(hh, bhh[nt][3], ag[nt], 0, 0, 0);
                ag[nt] = __builtin_amdgcn_mfma_f32_16x16x32_bf16(hl, bhh[nt][3], ag[nt], 0, 0, 0);
                ag[nt] = __builtin_amdgcn_mfma_f32_16x16x32_bf16(hh, bhl[nt][3], ag[nt], 0, 0, 0);
            }
        }
        __builtin_amdgcn_s_setprio(0);

        // (e) publish gh partials
#pragma unroll
        for (int s = 0; s < 3; ++s)
#pragma unroll
            for (int i = 0; i < 4; ++i)
                pgh[kw][s][prow + i][lrow] = ag[s][i];
        __syncthreads();

        // (f) epilogue (waves 0-3): gates, deferred out(t-1), premasked h(t+1)
        if (tid < 256) {
            float h0 = 0.f, h1 = 0.f, h2 = 0.f;
#pragma unroll
            for (int k = 0; k < 8; ++k) {
                h0 += pgh[k][0][eb][ej];
                h1 += pgh[k][1][eb][ej];
                h2 += pgh[k][2][eb][ej];
            }
            float r = 1.f / (1.f + __expf(-(g0 + bi_r + h0)));
            float z = 1.f / (1.f + __expf(-(g1 + bi_z + h1)));
            float pre = g2 + bi_n + r * (h2 + bh_n);
            float e2 = __expf(2.f * pre);
            float n = 1.f - 2.f / (e2 + 1.f);
            float hnew = (1.f - z) * n + z * h_local;

            if (t) out[(size_t)(t - 1) * 65536u + brow * DD + ce] = ys_prev;
            ys_prev = hnew;

            if (t < TT - 1) {
                float heff = (rsv != 0u) ? 0.f : hnew;   // rsv drained by WAITN(6)
                h_local = heff;
                unsigned short ph = f2bf(heff);
                unsigned short pl = f2bf(heff - bf2f(ph));
                __hip_atomic_store(h_hi[cur ^ 1] + brow * DD + ce, ph,
                                   __ATOMIC_RELAXED, __HIP_MEMORY_SCOPE_AGENT);
                __hip_atomic_store(h_lo[cur ^ 1] + brow * DD + ce, pl,
                                   __ATOMIC_RELAXED, __HIP_MEMORY_SCOPE_AGENT);
            }
        }
        asm volatile("" ::: "memory");   // pin store -> x-issue program order

        // (g) issue x(t+1) AFTER stores (drains under next poll, off arrive path)
        u32x4 xf[8];
        if (t < TT - 1) {
            const unsigned* xpl = outw + (size_t)(t + 1) * 65536u;
#pragma unroll
            for (int kt = 0; kt < 4; ++kt) {
                ld16(xf[2 * kt],     xpl + xwbase + kt * 16);
                ld16(xf[2 * kt + 1], xpl + xwbase + 8192u + kt * 16);
            }
        }

        // (h) producer waves: drain own stores, rendezvous in LDS; the 4th wave
        //     publishes ONE +4 arrival for the whole WG (8 RMWs/line/step).
        if (kw < 4 && t < TT - 1) {
            WAITN(8);
            if (lane == 0) {
                int old = atomicAdd(&wgarr, 1);
                if ((old & 3) == 3)
                    __hip_atomic_fetch_add(arrctr, 4u, __ATOMIC_RELAXED, __HIP_MEMORY_SCOPE_AGENT);
            }
        }

        // (i) tail: drain x, gi(t+1) MFMAs, publish, sync
        if (t < TT - 1) {
            WAITN(0);
            f32x4 ai[3] = {f32x4{0}, f32x4{0}, f32x4{0}};
#pragma unroll
            for (int kt = 0; kt < 4; ++kt) {
                short8 xh = __builtin_bit_cast(short8, xf[2 * kt]);
                short8 xl = __builtin_bit_cast(short8, xf[2 * kt + 1]);
#pragma unroll
                for (int nt = 0; nt < 3; ++nt)
                    ai[nt] = __builtin_amdgcn_mfma_f32_16x16x32_bf16(xh, bih[nt][kt], ai[nt], 0, 0, 0);
#pragma unroll
                for (int nt = 0; nt < 3; ++nt)
                    ai[nt] = __builtin_amdgcn_mfma_f32_16x16x32_bf16(xl, bih[nt][kt], ai[nt], 0, 0, 0);
            }
#pragma unroll
            for (int s = 0; s < 3; ++s)
#pragma unroll
                for (int i = 0; i < 4; ++i)
                    pgi[kw][s][prow + i][lrow] = ai[s][i];
            __syncthreads();
        }
    }

    if (tid < 256)
        out[(size_t)(TT - 1) * 65536u + brow * DD + ce] = ys_prev;
}

extern "C" void kernel_launch(void* const* d_in, const int* in_sizes, int n_in,
                              void* d_out, int out_size, void* d_ws, size_t ws_size,
                              hipStream_t stream) {
    const float* x = (const float*)d_in[0];
    const float* Wi = (const float*)d_in[1];
    const float* bi = (const float*)d_in[2];
    const float* Wh = (const float*)d_in[3];
    const float* bhn = (const float*)d_in[4];
    const unsigned char* resets = (const unsigned char*)d_in[5];
    float* out = (float*)d_out;
    unsigned char* ws = (unsigned char*)d_ws;

    if (ws_size < WS_NEED) return;

    hipLaunchKernelGGL(pack_x_kernel, dim3(16384), dim3(256), 0, stream, x, (unsigned*)out);
    hipLaunchKernelGGL(prep_kernel, dim3(257), dim3(256), 0, stream, resets, ws);

    void* args[] = {(void*)&Wi, (void*)&bi, (void*)&Wh, (void*)&bhn,
                    (void*)&resets, (void*)&out, (void*)&ws};
    hipError_t err = hipLaunchCooperativeKernel((const void*)gru_kernel, dim3(256), dim3(512),
                                                args, 0, stream);
    if (err != hipSuccess) {
        hipLaunchKernelGGL(gru_kernel, dim3(256), dim3(512), 0, stream,
                           Wi, bi, Wh, bhn, resets, out, ws);
    }
}